// Round 1
// baseline (483.706 us; speedup 1.0000x reference)
//
#include <hip/hip_runtime.h>

// Sizes (fixed by the problem)
#define FR   8000    // B*T frames
#define DD   512     // latent dim
#define CK   1024    // codebook size
#define KSZ  320     // conv kernel == stride
#define TT   500     // frames per batch item
#define NB   16      // batch

// ---------------------------------------------------------------------------
// Encoder GEMM: emb[f,d] = sum_k wav[f*320+k] * enc_w[d*320+k] + enc_b[d]
// Tile 64x64, BK=32, thread tile 4x4 (256 threads)
// ---------------------------------------------------------------------------
__global__ __launch_bounds__(256) void k_enc(const float* __restrict__ wav,
                                             const float* __restrict__ ew,
                                             const float* __restrict__ eb,
                                             float* __restrict__ emb) {
    __shared__ __align__(16) float As[32][68];  // [k][frame]
    __shared__ __align__(16) float Bs[32][68];  // [k][d]
    const int f0 = blockIdx.x * 64;
    const int d0 = blockIdx.y * 64;
    const int tid = threadIdx.x;
    const int ty = tid >> 4, tx = tid & 15;
    float acc[4][4] = {};
    for (int kt = 0; kt < KSZ; kt += 32) {
#pragma unroll
        for (int p = 0; p < 2; ++p) {
            int row = (tid >> 3) + 32 * p;      // frame / d row
            int c4  = (tid & 7) * 4;            // k offset
            float4 v = *reinterpret_cast<const float4*>(&wav[(f0 + row) * KSZ + kt + c4]);
            As[c4 + 0][row] = v.x; As[c4 + 1][row] = v.y;
            As[c4 + 2][row] = v.z; As[c4 + 3][row] = v.w;
            float4 w = *reinterpret_cast<const float4*>(&ew[(d0 + row) * KSZ + kt + c4]);
            Bs[c4 + 0][row] = w.x; Bs[c4 + 1][row] = w.y;
            Bs[c4 + 2][row] = w.z; Bs[c4 + 3][row] = w.w;
        }
        __syncthreads();
#pragma unroll 8
        for (int k = 0; k < 32; ++k) {
            float4 a = *reinterpret_cast<const float4*>(&As[k][4 * ty]);
            float4 b = *reinterpret_cast<const float4*>(&Bs[k][4 * tx]);
            float av[4] = {a.x, a.y, a.z, a.w};
            float bv[4] = {b.x, b.y, b.z, b.w};
#pragma unroll
            for (int i = 0; i < 4; ++i)
#pragma unroll
                for (int j = 0; j < 4; ++j) acc[i][j] += av[i] * bv[j];
        }
        __syncthreads();
    }
    float4 bias = *reinterpret_cast<const float4*>(&eb[d0 + 4 * tx]);
    float bb[4] = {bias.x, bias.y, bias.z, bias.w};
#pragma unroll
    for (int i = 0; i < 4; ++i) {
        float4 o;
        o.x = acc[i][0] + bb[0]; o.y = acc[i][1] + bb[1];
        o.z = acc[i][2] + bb[2]; o.w = acc[i][3] + bb[3];
        *reinterpret_cast<float4*>(&emb[(f0 + 4 * ty + i) * DD + d0 + 4 * tx]) = o;
    }
}

// ---------------------------------------------------------------------------
// time_avg[b,d] = mean_t emb[b,t,d]
// ---------------------------------------------------------------------------
__global__ __launch_bounds__(256) void k_tavg(const float* __restrict__ emb,
                                              float* __restrict__ tavg) {
    const int b = blockIdx.y;
    const int d0 = blockIdx.x * 64;
    const int dl = threadIdx.x & 63, tg = threadIdx.x >> 6;
    float s = 0.f;
    for (int t = tg; t < TT; t += 4) s += emb[(b * TT + t) * DD + d0 + dl];
    __shared__ float red[4][64];
    red[tg][dl] = s;
    __syncthreads();
    if (tg == 0)
        tavg[b * DD + d0 + dl] =
            (red[0][dl] + red[1][dl] + red[2][dl] + red[3][dl]) * (1.0f / TT);
}

// ---------------------------------------------------------------------------
// codebook squared norms
// ---------------------------------------------------------------------------
__global__ __launch_bounds__(256) void k_cbnorm(const float* __restrict__ cb,
                                                float* __restrict__ cbn) {
    const int c = blockIdx.x * 32 + (threadIdx.x >> 3);
    const int l = threadIdx.x & 7;
    float s = 0.f;
    for (int j = l * 4; j < DD; j += 32) {
        float4 v = *reinterpret_cast<const float4*>(&cb[c * DD + j]);
        s += v.x * v.x + v.y * v.y + v.z * v.z + v.w * v.w;
    }
    s += __shfl_xor(s, 1);
    s += __shfl_xor(s, 2);
    s += __shfl_xor(s, 4);
    if (l == 0) cbn[c] = s;
}

// ---------------------------------------------------------------------------
// cond = tavg @ lin_w^T + lin_b ; gb = cond @ film_w^T + film_b  (per batch b)
// ---------------------------------------------------------------------------
__global__ __launch_bounds__(256) void k_condfilm(const float* __restrict__ tavg,
                                                  const float* __restrict__ lw,
                                                  const float* __restrict__ lb,
                                                  const float* __restrict__ fw,
                                                  const float* __restrict__ fb,
                                                  float* __restrict__ gbv) {
    __shared__ float sm[DD];
    __shared__ float sc[DD];
    const int b = blockIdx.x, tid = threadIdx.x;
    sm[tid] = tavg[b * DD + tid];
    sm[tid + 256] = tavg[b * DD + tid + 256];
    __syncthreads();
#pragma unroll
    for (int r = 0; r < 2; ++r) {
        int i = tid + 256 * r;
        float s = lb[i];
        for (int j = 0; j < DD; j += 4) {
            float4 w = *reinterpret_cast<const float4*>(&lw[i * DD + j]);
            s += sm[j] * w.x + sm[j + 1] * w.y + sm[j + 2] * w.z + sm[j + 3] * w.w;
        }
        sc[i] = s;
    }
    __syncthreads();
#pragma unroll
    for (int r = 0; r < 4; ++r) {
        int o = tid + 256 * r;
        float s = fb[o];
        for (int j = 0; j < DD; j += 4) {
            float4 w = *reinterpret_cast<const float4*>(&fw[o * DD + j]);
            s += sc[j] * w.x + sc[j + 1] * w.y + sc[j + 2] * w.z + sc[j + 3] * w.w;
        }
        gbv[b * 2 * DD + o] = s;
    }
}

// ---------------------------------------------------------------------------
// VQ distances + fused partial argmin.
// Block: 32 frames x 512 codes (blockIdx.y selects codebook half), BK=16.
// Thread: 4 frames x 16 codes (codes strided by 32 for bank-conflict-free LDS).
// score = ||c||^2 - 2 * x.c   (||x||^2 constant per frame -> irrelevant)
// ---------------------------------------------------------------------------
__global__ __launch_bounds__(256) void k_dist(const float* __restrict__ emb,
                                              const float* __restrict__ cb,
                                              const float* __restrict__ cbn,
                                              float* __restrict__ pmin,
                                              int* __restrict__ pidx) {
    __shared__ __align__(16) float Xs[16][36];    // [k][frame]
    __shared__ __align__(16) float Cs[16][516];   // [k][code]
    const int f0 = blockIdx.x * 32;
    const int cbase = blockIdx.y * 512;
    const int tid = threadIdx.x;
    const int ty = tid >> 5, tx = tid & 31;
    float acc[4][16] = {};
    for (int kt = 0; kt < DD; kt += 16) {
#pragma unroll
        for (int p = 0; p < 2; ++p) {
            int f = (tid >> 4) + 16 * p, c = tid & 15;
            Xs[c][f] = emb[(f0 + f) * DD + kt + c];
        }
#pragma unroll
        for (int p = 0; p < 8; ++p) {
            int c = (tid >> 2) + 64 * p, q = (tid & 3) * 4;
            float4 v = *reinterpret_cast<const float4*>(&cb[(cbase + c) * DD + kt + q]);
            Cs[q + 0][c] = v.x; Cs[q + 1][c] = v.y;
            Cs[q + 2][c] = v.z; Cs[q + 3][c] = v.w;
        }
        __syncthreads();
#pragma unroll 4
        for (int k = 0; k < 16; ++k) {
            float4 xa = *reinterpret_cast<const float4*>(&Xs[k][4 * ty]);
            float xv[4] = {xa.x, xa.y, xa.z, xa.w};
#pragma unroll
            for (int i = 0; i < 16; ++i) {
                float cv = Cs[k][tx + 32 * i];
                acc[0][i] += xv[0] * cv;
                acc[1][i] += xv[1] * cv;
                acc[2][i] += xv[2] * cv;
                acc[3][i] += xv[3] * cv;
            }
        }
        __syncthreads();
    }
#pragma unroll
    for (int fi = 0; fi < 4; ++fi) {
        float best = 3.4e38f;
        int bidx = 0;
#pragma unroll
        for (int i = 0; i < 16; ++i) {
            int c = cbase + tx + 32 * i;
            float s = cbn[c] - 2.0f * acc[fi][i];
            if (s < best || (s == best && c < bidx)) { best = s; bidx = c; }
        }
#pragma unroll
        for (int m = 16; m >= 1; m >>= 1) {
            float os = __shfl_xor(best, m);
            int   oi = __shfl_xor(bidx, m);
            if (os < best || (os == best && oi < bidx)) { best = os; bidx = oi; }
        }
        if (tx == 0) {
            int f = f0 + 4 * ty + fi;
            pmin[f * 2 + blockIdx.y] = best;
            pidx[f * 2 + blockIdx.y] = bidx;
        }
    }
}

__global__ void k_combine(const float* __restrict__ pmin,
                          const int* __restrict__ pidx,
                          int* __restrict__ codes) {
    int f = blockIdx.x * 256 + threadIdx.x;
    if (f < FR) {
        float s0 = pmin[f * 2], s1 = pmin[f * 2 + 1];
        int i0 = pidx[f * 2], i1 = pidx[f * 2 + 1];
        codes[f] = (s1 < s0) ? i1 : i0;  // tie -> lower index (half 0)
    }
}

// ---------------------------------------------------------------------------
// Decoder: out[f*320+s] = sum_d (gamma[b,d]*cb[code[f],d]+beta[b,d]) * dw[d][319-s] + db
// Tile 64 frames x 64 s, BK=32, thread 4x4. Gather+FiLM fused into A-staging.
// ---------------------------------------------------------------------------
__global__ __launch_bounds__(256) void k_dec(const int* __restrict__ codes,
                                             const float* __restrict__ cb,
                                             const float* __restrict__ gbv,
                                             const float* __restrict__ dw,
                                             const float* __restrict__ db,
                                             float* __restrict__ out) {
    __shared__ __align__(16) float Am[32][68];  // [k][frame] modulated
    __shared__ __align__(16) float Bs[32][68];  // [k][s]  (flipped dec_w)
    const int f0 = blockIdx.x * 64;
    const int s0 = blockIdx.y * 64;
    const int tid = threadIdx.x;
    const int ty = tid >> 4, tx = tid & 15;
    float acc[4][4] = {};
    for (int kt = 0; kt < DD; kt += 32) {
#pragma unroll
        for (int p = 0; p < 2; ++p) {
            int f = (tid >> 3) + 32 * p;
            int c4 = (tid & 7) * 4;
            int fg = f0 + f;
            int code = codes[fg];
            int b = fg / TT;
            int kg = kt + c4;
            float4 v  = *reinterpret_cast<const float4*>(&cb[code * DD + kg]);
            float4 g  = *reinterpret_cast<const float4*>(&gbv[b * 2 * DD + kg]);
            float4 be = *reinterpret_cast<const float4*>(&gbv[b * 2 * DD + DD + kg]);
            Am[c4 + 0][f] = g.x * v.x + be.x;
            Am[c4 + 1][f] = g.y * v.y + be.y;
            Am[c4 + 2][f] = g.z * v.z + be.z;
            Am[c4 + 3][f] = g.w * v.w + be.w;
        }
#pragma unroll
        for (int p = 0; p < 2; ++p) {
            int r = tid >> 3;                 // k-local row 0..31
            int sl = (tid & 7) * 4 + 32 * p;  // s-local
            int kg = kt + r;
            int sg = s0 + sl;
#pragma unroll
            for (int j = 0; j < 4; ++j)
                Bs[r][sl + j] = dw[kg * KSZ + (KSZ - 1) - (sg + j)];
        }
        __syncthreads();
#pragma unroll 8
        for (int k = 0; k < 32; ++k) {
            float4 a = *reinterpret_cast<const float4*>(&Am[k][4 * ty]);
            float4 b = *reinterpret_cast<const float4*>(&Bs[k][4 * tx]);
            float av[4] = {a.x, a.y, a.z, a.w};
            float bv[4] = {b.x, b.y, b.z, b.w};
#pragma unroll
            for (int i = 0; i < 4; ++i)
#pragma unroll
                for (int j = 0; j < 4; ++j) acc[i][j] += av[i] * bv[j];
        }
        __syncthreads();
    }
    const float d0 = db[0];
#pragma unroll
    for (int i = 0; i < 4; ++i) {
        float4 o;
        o.x = acc[i][0] + d0; o.y = acc[i][1] + d0;
        o.z = acc[i][2] + d0; o.w = acc[i][3] + d0;
        *reinterpret_cast<float4*>(&out[(f0 + 4 * ty + i) * KSZ + s0 + 4 * tx]) = o;
    }
}

// ---------------------------------------------------------------------------
extern "C" void kernel_launch(void* const* d_in, const int* in_sizes, int n_in,
                              void* d_out, int out_size, void* d_ws, size_t ws_size,
                              hipStream_t stream) {
    const float* wav    = (const float*)d_in[0];
    const float* enc_w  = (const float*)d_in[1];
    const float* enc_b  = (const float*)d_in[2];
    const float* cb     = (const float*)d_in[3];
    const float* lin_w  = (const float*)d_in[4];
    const float* lin_b  = (const float*)d_in[5];
    const float* film_w = (const float*)d_in[6];
    const float* film_b = (const float*)d_in[7];
    const float* dec_w  = (const float*)d_in[8];
    const float* dec_b  = (const float*)d_in[9];
    float* out = (float*)d_out;

    // ws layout (floats): ~16.65 MB total
    float* ws    = (float*)d_ws;
    float* emb   = ws;                    // FR*DD = 4,096,000
    float* tavg  = emb + (size_t)FR * DD; // NB*DD = 8192
    float* gbv   = tavg + NB * DD;        // NB*2*DD = 16384
    float* cbn   = gbv + NB * 2 * DD;     // CK = 1024
    float* pmin  = cbn + CK;              // FR*2 = 16000
    int*   pidx  = (int*)(pmin + FR * 2); // FR*2 = 16000
    int*   codes = pidx + FR * 2;         // FR = 8000

    k_enc<<<dim3(125, 8), 256, 0, stream>>>(wav, enc_w, enc_b, emb);
    k_cbnorm<<<dim3(32), 256, 0, stream>>>(cb, cbn);
    k_tavg<<<dim3(8, NB), 256, 0, stream>>>(emb, tavg);
    k_condfilm<<<dim3(NB), 256, 0, stream>>>(tavg, lin_w, lin_b, film_w, film_b, gbv);
    k_dist<<<dim3(250, 2), 256, 0, stream>>>(emb, cb, cbn, pmin, pidx);
    k_combine<<<dim3(32), 256, 0, stream>>>(pmin, pidx, codes);
    k_dec<<<dim3(125, 5), 256, 0, stream>>>(codes, cb, gbv, dec_w, dec_b, out);
}

// Round 2
// 304.376 us; speedup vs baseline: 1.5892x; 1.5892x over previous
//
#include <hip/hip_runtime.h>

#define FR   8000
#define FRP  8064    // padded to 63*128
#define DD   512
#define CK   1024
#define KSZ  320
#define TT   500
#define NB   16

typedef unsigned int u32;
typedef unsigned short u16;
typedef __attribute__((ext_vector_type(8))) short b8;   // 8 x bf16 bits
typedef __attribute__((ext_vector_type(4))) float f4;

__device__ __forceinline__ float bf2f(u16 h) {
    u32 u = ((u32)h) << 16;
    return __builtin_bit_cast(float, u);
}
__device__ __forceinline__ u16 f2bf(float f) {  // RNE
    u32 u = __builtin_bit_cast(u32, f);
    u32 r = u + 0x7FFFu + ((u >> 16) & 1u);
    return (u16)(r >> 16);
}

__device__ __forceinline__ void gld16(const u16* g, u16* s) {
    __builtin_amdgcn_global_load_lds(
        (const __attribute__((address_space(1))) u32*)g,
        (__attribute__((address_space(3))) u32*)s, 16, 0, 0);
}

__device__ __forceinline__ f4 mfma(b8 a, b8 b, f4 c) {
    return __builtin_amdgcn_mfma_f32_16x16x32_bf16(a, b, c, 0, 0, 0);
}

// split 8 floats -> hi/lo bf16x8, write to LDS
__device__ __forceinline__ void split8(float4 a, float4 b, u16* dh, u16* dl) {
    float xs[8] = {a.x, a.y, a.z, a.w, b.x, b.y, b.z, b.w};
    union { u16 u[8]; b8 v; } H, L;
#pragma unroll
    for (int i = 0; i < 8; ++i) {
        u16 h = f2bf(xs[i]);
        H.u[i] = h;
        L.u[i] = f2bf(xs[i] - bf2f(h));
    }
    *(b8*)dh = H.v;
    *(b8*)dl = L.v;
}

// ---------------------------------------------------------------------------
// generic fp32 -> bf16 hi/lo split (n divisible by 2048)
// ---------------------------------------------------------------------------
__global__ __launch_bounds__(256) void k_split(const float* __restrict__ src,
                                               u16* __restrict__ h,
                                               u16* __restrict__ l) {
    int i = (blockIdx.x * 256 + threadIdx.x) * 8;
    float4 a = *(const float4*)&src[i];
    float4 b = *(const float4*)&src[i + 4];
    split8(a, b, &h[i], &l[i]);
}

// dwf[s][d] = dec_w[d][319-s], padded to 384 rows with zeros; split
__global__ __launch_bounds__(256) void k_dwf(const float* __restrict__ dw,
                                             u16* __restrict__ h,
                                             u16* __restrict__ l) {
    int idx = blockIdx.x * 256 + threadIdx.x;  // 384*512
    int s = idx >> 9, d = idx & 511;
    float v = (s < KSZ) ? dw[d * KSZ + (KSZ - 1) - s] : 0.f;
    u16 hi = f2bf(v);
    h[idx] = hi;
    l[idx] = f2bf(v - bf2f(hi));
}

__global__ __launch_bounds__(256) void k_cbnorm(const float* __restrict__ cb,
                                                float* __restrict__ cbn) {
    const int c = blockIdx.x * 32 + (threadIdx.x >> 3);
    const int l = threadIdx.x & 7;
    float s = 0.f;
    for (int j = l * 4; j < DD; j += 32) {
        float4 v = *(const float4*)&cb[c * DD + j];
        s += v.x * v.x + v.y * v.y + v.z * v.z + v.w * v.w;
    }
    s += __shfl_xor(s, 1);
    s += __shfl_xor(s, 2);
    s += __shfl_xor(s, 4);
    if (l == 0) cbn[c] = s;
}

// ---------------------------------------------------------------------------
// Encoder MFMA GEMM: emb[f,d] = wav[f,:] . enc_w[d,:] + eb[d]
// A: wav fp32 (on-the-fly split, reg-staged); B: pre-split enc_w.
// 128x128 tile, BK=32, 4 waves (2x2), wave tile 64x64.
// ---------------------------------------------------------------------------
__global__ __launch_bounds__(256, 2) void k_enc(const float* __restrict__ wav,
                                                const u16* __restrict__ Bhg,
                                                const u16* __restrict__ Blg,
                                                const float* __restrict__ eb,
                                                u16* __restrict__ embh,
                                                u16* __restrict__ embl) {
    __shared__ __align__(16) u16 Ah[4096], Al[4096], Bh[4096], Bl[4096];
    const int tid = threadIdx.x;
    const int l = tid & 63, w = tid >> 6, wm = w >> 1, wn = w & 1;
    const int lane16 = l & 15, laneK = l >> 4;
    const int f0 = blockIdx.x * 128, d0 = blockIdx.y * 128;

    // B staging decode (gload_lds, swizzled source)
    const int p0 = w * 128 + l, p1 = p0 + 64;
    const int r0 = p0 >> 2, q0 = (p0 & 3) ^ ((r0 >> 1) & 3);
    const int r1 = p1 >> 2, q1 = (p1 & 3) ^ ((r1 >> 1) & 3);
    const u16* gB0h = Bhg + (size_t)(d0 + r0) * KSZ + q0 * 8;
    const u16* gB1h = Bhg + (size_t)(d0 + r1) * KSZ + q1 * 8;
    const u16* gB0l = Blg + (size_t)(d0 + r0) * KSZ + q0 * 8;
    const u16* gB1l = Blg + (size_t)(d0 + r1) * KSZ + q1 * 8;
    u16* lB0h = Bh + w * 1024; u16* lB1h = lB0h + 512;
    u16* lB0l = Bl + w * 1024; u16* lB1l = lB0l + 512;

    // A staging decode (reg convert)
    const int pa0 = tid, pa1 = tid + 256;
    const int ra0 = pa0 >> 2, qa0 = (pa0 & 3) ^ ((ra0 >> 1) & 3);
    const int ra1 = pa1 >> 2, qa1 = (pa1 & 3) ^ ((ra1 >> 1) & 3);
    int fr0 = f0 + ra0; if (fr0 > FR - 1) fr0 = FR - 1;
    int fr1 = f0 + ra1; if (fr1 > FR - 1) fr1 = FR - 1;
    const float* wv0 = wav + (size_t)fr0 * KSZ + qa0 * 8;
    const float* wv1 = wav + (size_t)fr1 * KSZ + qa1 * 8;
    u16* la0h = Ah + pa0 * 8; u16* la0l = Al + pa0 * 8;
    u16* la1h = Ah + pa1 * 8; u16* la1l = Al + pa1 * 8;

    int offA[4], offB[4];
#pragma unroll
    for (int i = 0; i < 4; ++i) {
        int ra = wm * 64 + i * 16 + lane16;
        offA[i] = (ra * 4 + (laneK ^ ((ra >> 1) & 3))) * 8;
        int rb = wn * 64 + i * 16 + lane16;
        offB[i] = (rb * 4 + (laneK ^ ((rb >> 1) & 3))) * 8;
    }

    f4 zero = {0.f, 0.f, 0.f, 0.f};
    f4 acc[4][4];
#pragma unroll
    for (int i = 0; i < 4; ++i)
#pragma unroll
        for (int j = 0; j < 4; ++j) acc[i][j] = zero;

    for (int kt = 0; kt < KSZ; kt += 32) {
        gld16(gB0h + kt, lB0h); gld16(gB1h + kt, lB1h);
        gld16(gB0l + kt, lB0l); gld16(gB1l + kt, lB1l);
        float4 x0 = *(const float4*)(wv0 + kt);
        float4 x1 = *(const float4*)(wv0 + kt + 4);
        float4 y0 = *(const float4*)(wv1 + kt);
        float4 y1 = *(const float4*)(wv1 + kt + 4);
        split8(x0, x1, la0h, la0l);
        split8(y0, y1, la1h, la1l);
        __syncthreads();
        b8 ah[4], al[4], bh[4], bl[4];
#pragma unroll
        for (int i = 0; i < 4; ++i) {
            ah[i] = *(const b8*)(Ah + offA[i]);
            al[i] = *(const b8*)(Al + offA[i]);
            bh[i] = *(const b8*)(Bh + offB[i]);
            bl[i] = *(const b8*)(Bl + offB[i]);
        }
#pragma unroll
        for (int mi = 0; mi < 4; ++mi)
#pragma unroll
            for (int ni = 0; ni < 4; ++ni) {
                acc[mi][ni] = mfma(ah[mi], bh[ni], acc[mi][ni]);
                acc[mi][ni] = mfma(ah[mi], bl[ni], acc[mi][ni]);
                acc[mi][ni] = mfma(al[mi], bh[ni], acc[mi][ni]);
            }
        __syncthreads();
    }

    float ebv[4];
#pragma unroll
    for (int ni = 0; ni < 4; ++ni) ebv[ni] = eb[d0 + wn * 64 + ni * 16 + lane16];
#pragma unroll
    for (int mi = 0; mi < 4; ++mi)
#pragma unroll
        for (int q = 0; q < 4; ++q) {
            int f = f0 + wm * 64 + mi * 16 + laneK * 4 + q;
#pragma unroll
            for (int ni = 0; ni < 4; ++ni) {
                int d = d0 + wn * 64 + ni * 16 + lane16;
                float v = acc[mi][ni][q] + ebv[ni];
                u16 h = f2bf(v);
                size_t o = (size_t)f * DD + d;
                embh[o] = h;
                embl[o] = f2bf(v - bf2f(h));
            }
        }
}

// ---------------------------------------------------------------------------
// time_avg from split emb
// ---------------------------------------------------------------------------
__global__ __launch_bounds__(256) void k_tavg(const u16* __restrict__ eh,
                                              const u16* __restrict__ el,
                                              float* __restrict__ tavg) {
    const int b = blockIdx.y;
    const int d0 = blockIdx.x * 64;
    const int dl = threadIdx.x & 63, tg = threadIdx.x >> 6;
    float s = 0.f;
    for (int t = tg; t < TT; t += 4) {
        size_t o = (size_t)(b * TT + t) * DD + d0 + dl;
        s += bf2f(eh[o]) + bf2f(el[o]);
    }
    __shared__ float red[4][64];
    red[tg][dl] = s;
    __syncthreads();
    if (tg == 0)
        tavg[b * DD + d0 + dl] =
            (red[0][dl] + red[1][dl] + red[2][dl] + red[3][dl]) * (1.0f / TT);
}

__global__ __launch_bounds__(256) void k_condfilm(const float* __restrict__ tavg,
                                                  const float* __restrict__ lw,
                                                  const float* __restrict__ lb,
                                                  const float* __restrict__ fw,
                                                  const float* __restrict__ fb,
                                                  float* __restrict__ gbv) {
    __shared__ float sm[DD];
    __shared__ float sc[DD];
    const int b = blockIdx.x, tid = threadIdx.x;
    sm[tid] = tavg[b * DD + tid];
    sm[tid + 256] = tavg[b * DD + tid + 256];
    __syncthreads();
#pragma unroll
    for (int r = 0; r < 2; ++r) {
        int i = tid + 256 * r;
        float s = lb[i];
        for (int j = 0; j < DD; j += 4) {
            float4 w = *(const float4*)&lw[i * DD + j];
            s += sm[j] * w.x + sm[j + 1] * w.y + sm[j + 2] * w.z + sm[j + 3] * w.w;
        }
        sc[i] = s;
    }
    __syncthreads();
#pragma unroll
    for (int r = 0; r < 4; ++r) {
        int o = tid + 256 * r;
        float s = fb[o];
        for (int j = 0; j < DD; j += 4) {
            float4 w = *(const float4*)&fw[o * DD + j];
            s += sc[j] * w.x + sc[j + 1] * w.y + sc[j + 2] * w.z + sc[j + 3] * w.w;
        }
        gbv[b * 2 * DD + o] = s;
    }
}

// ---------------------------------------------------------------------------
// VQ dist MFMA + fused per-block argmin.  S[f,c] = emb[f,:].cb[c,:]
// score = cbn[c] - 2 S.  Grid (63, 8): 128 frames x 128 codes per block.
// ---------------------------------------------------------------------------
__global__ __launch_bounds__(256, 2) void k_dist(const u16* __restrict__ Ahg,
                                                 const u16* __restrict__ Alg,
                                                 const u16* __restrict__ Bhg,
                                                 const u16* __restrict__ Blg,
                                                 const float* __restrict__ cbn,
                                                 float* __restrict__ pmin,
                                                 int* __restrict__ pidx) {
    __shared__ __align__(16) u16 Ah[4096], Al[4096], Bh[4096], Bl[4096];
    __shared__ float s_best[128][2];
    __shared__ int s_bidx[128][2];
    const int tid = threadIdx.x;
    const int l = tid & 63, w = tid >> 6, wm = w >> 1, wn = w & 1;
    const int lane16 = l & 15, laneK = l >> 4;
    const int f0 = blockIdx.x * 128, c0 = blockIdx.y * 128;

    const int p0 = w * 128 + l, p1 = p0 + 64;
    const int r0 = p0 >> 2, q0 = (p0 & 3) ^ ((r0 >> 1) & 3);
    const int r1 = p1 >> 2, q1 = (p1 & 3) ^ ((r1 >> 1) & 3);
    const u16* gA0h = Ahg + (size_t)(f0 + r0) * DD + q0 * 8;
    const u16* gA1h = Ahg + (size_t)(f0 + r1) * DD + q1 * 8;
    const u16* gA0l = Alg + (size_t)(f0 + r0) * DD + q0 * 8;
    const u16* gA1l = Alg + (size_t)(f0 + r1) * DD + q1 * 8;
    const u16* gB0h = Bhg + (size_t)(c0 + r0) * DD + q0 * 8;
    const u16* gB1h = Bhg + (size_t)(c0 + r1) * DD + q1 * 8;
    const u16* gB0l = Blg + (size_t)(c0 + r0) * DD + q0 * 8;
    const u16* gB1l = Blg + (size_t)(c0 + r1) * DD + q1 * 8;
    u16* lA0h = Ah + w * 1024; u16* lA1h = lA0h + 512;
    u16* lA0l = Al + w * 1024; u16* lA1l = lA0l + 512;
    u16* lB0h = Bh + w * 1024; u16* lB1h = lB0h + 512;
    u16* lB0l = Bl + w * 1024; u16* lB1l = lB0l + 512;

    int offA[4], offB[4];
#pragma unroll
    for (int i = 0; i < 4; ++i) {
        int ra = wm * 64 + i * 16 + lane16;
        offA[i] = (ra * 4 + (laneK ^ ((ra >> 1) & 3))) * 8;
        int rb = wn * 64 + i * 16 + lane16;
        offB[i] = (rb * 4 + (laneK ^ ((rb >> 1) & 3))) * 8;
    }

    f4 zero = {0.f, 0.f, 0.f, 0.f};
    f4 acc[4][4];
#pragma unroll
    for (int i = 0; i < 4; ++i)
#pragma unroll
        for (int j = 0; j < 4; ++j) acc[i][j] = zero;

    for (int kt = 0; kt < DD; kt += 32) {
        gld16(gA0h + kt, lA0h); gld16(gA1h + kt, lA1h);
        gld16(gA0l + kt, lA0l); gld16(gA1l + kt, lA1l);
        gld16(gB0h + kt, lB0h); gld16(gB1h + kt, lB1h);
        gld16(gB0l + kt, lB0l); gld16(gB1l + kt, lB1l);
        __syncthreads();
        b8 ah[4], al[4], bh[4], bl[4];
#pragma unroll
        for (int i = 0; i < 4; ++i) {
            ah[i] = *(const b8*)(Ah + offA[i]);
            al[i] = *(const b8*)(Al + offA[i]);
            bh[i] = *(const b8*)(Bh + offB[i]);
            bl[i] = *(const b8*)(Bl + offB[i]);
        }
#pragma unroll
        for (int mi = 0; mi < 4; ++mi)
#pragma unroll
            for (int ni = 0; ni < 4; ++ni) {
                acc[mi][ni] = mfma(ah[mi], bh[ni], acc[mi][ni]);
                acc[mi][ni] = mfma(ah[mi], bl[ni], acc[mi][ni]);
                acc[mi][ni] = mfma(al[mi], bh[ni], acc[mi][ni]);
            }
        __syncthreads();
    }

    // fused argmin
    float cbv[4];
    int cidx[4];
#pragma unroll
    for (int ni = 0; ni < 4; ++ni) {
        cidx[ni] = c0 + wn * 64 + ni * 16 + lane16;
        cbv[ni] = cbn[cidx[ni]];
    }
#pragma unroll
    for (int mi = 0; mi < 4; ++mi)
#pragma unroll
        for (int q = 0; q < 4; ++q) {
            float best = 3.4e38f;
            int bi = 0x7fffffff;
#pragma unroll
            for (int ni = 0; ni < 4; ++ni) {
                float s = cbv[ni] - 2.0f * acc[mi][ni][q];
                if (s < best || (s == best && cidx[ni] < bi)) { best = s; bi = cidx[ni]; }
            }
#pragma unroll
            for (int m = 8; m >= 1; m >>= 1) {
                float os = __shfl_xor(best, m);
                int oi = __shfl_xor(bi, m);
                if (os < best || (os == best && oi < bi)) { best = os; bi = oi; }
            }
            if (lane16 == 0) {
                int rl = wm * 64 + mi * 16 + laneK * 4 + q;
                s_best[rl][wn] = best;
                s_bidx[rl][wn] = bi;
            }
        }
    __syncthreads();
    if (tid < 128) {
        float b0 = s_best[tid][0], b1 = s_best[tid][1];
        int i0 = s_bidx[tid][0], i1 = s_bidx[tid][1];
        bool t1 = (b1 < b0) || (b1 == b0 && i1 < i0);
        int f = f0 + tid;
        if (f < FR) {
            pmin[f * 8 + blockIdx.y] = t1 ? b1 : b0;
            pidx[f * 8 + blockIdx.y] = t1 ? i1 : i0;
        }
    }
}

__global__ void k_combine(const float* __restrict__ pmin,
                          const int* __restrict__ pidx,
                          int* __restrict__ codes) {
    int f = blockIdx.x * 256 + threadIdx.x;
    if (f < FR) {
        float best = pmin[f * 8];
        int bi = pidx[f * 8];
#pragma unroll
        for (int y = 1; y < 8; ++y) {
            float s = pmin[f * 8 + y];
            if (s < best) { best = s; bi = pidx[f * 8 + y]; }
        }
        codes[f] = bi;
    }
}

// ---------------------------------------------------------------------------
// modulated = gamma*cb[code] + beta, split to bf16 hi/lo (A operand of dec)
// ---------------------------------------------------------------------------
__global__ __launch_bounds__(256) void k_mod(const int* __restrict__ codes,
                                             const float* __restrict__ cb,
                                             const float* __restrict__ gbv,
                                             u16* __restrict__ mh,
                                             u16* __restrict__ ml) {
    int idx = blockIdx.x * 256 + threadIdx.x;  // 8000*64
    int f = idx >> 6, d = (idx & 63) * 8;
    int b = f / TT;
    int code = codes[f];
    const float* cp = cb + (size_t)code * DD + d;
    const float* gp = gbv + b * 2 * DD + d;
    const float* bp = gp + DD;
    union { u16 u[8]; b8 v; } H, L;
#pragma unroll
    for (int i = 0; i < 8; ++i) {
        float m = gp[i] * cp[i] + bp[i];
        u16 h = f2bf(m);
        H.u[i] = h;
        L.u[i] = f2bf(m - bf2f(h));
    }
    size_t o = (size_t)f * DD + d;
    *(b8*)&mh[o] = H.v;
    *(b8*)&ml[o] = L.v;
}

// ---------------------------------------------------------------------------
// Decoder MFMA GEMM: out[f*320+s] = mod[f,:].dwf[s,:] + db  (dwf pre-flipped)
// Grid (63, 3): 128 frames x 128 s (s padded to 384).
// ---------------------------------------------------------------------------
__global__ __launch_bounds__(256, 2) void k_dec(const u16* __restrict__ Ahg,
                                                const u16* __restrict__ Alg,
                                                const u16* __restrict__ Bhg,
                                                const u16* __restrict__ Blg,
                                                const float* __restrict__ db,
                                                float* __restrict__ out) {
    __shared__ __align__(16) u16 Ah[4096], Al[4096], Bh[4096], Bl[4096];
    const int tid = threadIdx.x;
    const int l = tid & 63, w = tid >> 6, wm = w >> 1, wn = w & 1;
    const int lane16 = l & 15, laneK = l >> 4;
    const int f0 = blockIdx.x * 128, s0 = blockIdx.y * 128;

    const int p0 = w * 128 + l, p1 = p0 + 64;
    const int r0 = p0 >> 2, q0 = (p0 & 3) ^ ((r0 >> 1) & 3);
    const int r1 = p1 >> 2, q1 = (p1 & 3) ^ ((r1 >> 1) & 3);
    const u16* gA0h = Ahg + (size_t)(f0 + r0) * DD + q0 * 8;
    const u16* gA1h = Ahg + (size_t)(f0 + r1) * DD + q1 * 8;
    const u16* gA0l = Alg + (size_t)(f0 + r0) * DD + q0 * 8;
    const u16* gA1l = Alg + (size_t)(f0 + r1) * DD + q1 * 8;
    const u16* gB0h = Bhg + (size_t)(s0 + r0) * DD + q0 * 8;
    const u16* gB1h = Bhg + (size_t)(s0 + r1) * DD + q1 * 8;
    const u16* gB0l = Blg + (size_t)(s0 + r0) * DD + q0 * 8;
    const u16* gB1l = Blg + (size_t)(s0 + r1) * DD + q1 * 8;
    u16* lA0h = Ah + w * 1024; u16* lA1h = lA0h + 512;
    u16* lA0l = Al + w * 1024; u16* lA1l = lA0l + 512;
    u16* lB0h = Bh + w * 1024; u16* lB1h = lB0h + 512;
    u16* lB0l = Bl + w * 1024; u16* lB1l = lB0l + 512;

    int offA[4], offB[4];
#pragma unroll
    for (int i = 0; i < 4; ++i) {
        int ra = wm * 64 + i * 16 + lane16;
        offA[i] = (ra * 4 + (laneK ^ ((ra >> 1) & 3))) * 8;
        int rb = wn * 64 + i * 16 + lane16;
        offB[i] = (rb * 4 + (laneK ^ ((rb >> 1) & 3))) * 8;
    }

    f4 zero = {0.f, 0.f, 0.f, 0.f};
    f4 acc[4][4];
#pragma unroll
    for (int i = 0; i < 4; ++i)
#pragma unroll
        for (int j = 0; j < 4; ++j) acc[i][j] = zero;

    for (int kt = 0; kt < DD; kt += 32) {
        gld16(gA0h + kt, lA0h); gld16(gA1h + kt, lA1h);
        gld16(gA0l + kt, lA0l); gld16(gA1l + kt, lA1l);
        gld16(gB0h + kt, lB0h); gld16(gB1h + kt, lB1h);
        gld16(gB0l + kt, lB0l); gld16(gB1l + kt, lB1l);
        __syncthreads();
        b8 ah[4], al[4], bh[4], bl[4];
#pragma unroll
        for (int i = 0; i < 4; ++i) {
            ah[i] = *(const b8*)(Ah + offA[i]);
            al[i] = *(const b8*)(Al + offA[i]);
            bh[i] = *(const b8*)(Bh + offB[i]);
            bl[i] = *(const b8*)(Bl + offB[i]);
        }
#pragma unroll
        for (int mi = 0; mi < 4; ++mi)
#pragma unroll
            for (int ni = 0; ni < 4; ++ni) {
                acc[mi][ni] = mfma(ah[mi], bh[ni], acc[mi][ni]);
                acc[mi][ni] = mfma(ah[mi], bl[ni], acc[mi][ni]);
                acc[mi][ni] = mfma(al[mi], bh[ni], acc[mi][ni]);
            }
        __syncthreads();
    }

    const float d0v = db[0];
#pragma unroll
    for (int mi = 0; mi < 4; ++mi)
#pragma unroll
        for (int q = 0; q < 4; ++q) {
            int f = f0 + wm * 64 + mi * 16 + laneK * 4 + q;
            if (f < FR) {
#pragma unroll
                for (int ni = 0; ni < 4; ++ni) {
                    int s = s0 + wn * 64 + ni * 16 + lane16;
                    if (s < KSZ) out[(size_t)f * KSZ + s] = acc[mi][ni][q] + d0v;
                }
            }
        }
}

// ---------------------------------------------------------------------------
extern "C" void kernel_launch(void* const* d_in, const int* in_sizes, int n_in,
                              void* d_out, int out_size, void* d_ws, size_t ws_size,
                              hipStream_t stream) {
    const float* wav    = (const float*)d_in[0];
    const float* enc_w  = (const float*)d_in[1];
    const float* enc_b  = (const float*)d_in[2];
    const float* cb     = (const float*)d_in[3];
    const float* lin_w  = (const float*)d_in[4];
    const float* lin_b  = (const float*)d_in[5];
    const float* film_w = (const float*)d_in[6];
    const float* film_b = (const float*)d_in[7];
    const float* dec_w  = (const float*)d_in[8];
    const float* dec_b  = (const float*)d_in[9];
    float* out = (float*)d_out;

    // ws layout (bytes), ~20.7 MB peak
    char* p = (char*)d_ws;
    u16* embh = (u16*)p;                 p += (size_t)FRP * DD * 2;   // 8.26MB
    u16* embl = (u16*)p;                 p += (size_t)FRP * DD * 2;
    u16* ewh  = (u16*)p;                 p += (size_t)DD * KSZ * 2;   // 0.33MB
    u16* ewl  = (u16*)p;                 p += (size_t)DD * KSZ * 2;
    u16* cbh  = (u16*)p;                 p += (size_t)CK * DD * 2;    // 1.05MB
    u16* cbl  = (u16*)p;                 p += (size_t)CK * DD * 2;
    u16* dwfh = (u16*)p;                 p += (size_t)384 * DD * 2;   // 0.39MB
    u16* dwfl = (u16*)p;                 p += (size_t)384 * DD * 2;
    float* cbn  = (float*)p;             p += CK * 4;
    float* tavg = (float*)p;             p += NB * DD * 4;
    float* gbv  = (float*)p;             p += NB * 2 * DD * 4;
    float* pmin = (float*)p;             p += FR * 8 * 4;
    int*   pidx = (int*)p;               p += FR * 8 * 4;
    int*   codes = (int*)p;              p += FR * 4;
    u16* modh = embh;  // alias: emb dead after k_dist/k_tavg
    u16* modl = embl;

    k_split<<<dim3(80), 256, 0, stream>>>(enc_w, ewh, ewl);       // 512*320
    k_split<<<dim3(256), 256, 0, stream>>>(cb, cbh, cbl);         // 1024*512
    k_dwf<<<dim3(768), 256, 0, stream>>>(dec_w, dwfh, dwfl);
    k_cbnorm<<<dim3(32), 256, 0, stream>>>(cb, cbn);
    k_enc<<<dim3(63, 4), 256, 0, stream>>>(wav, ewh, ewl, enc_b, embh, embl);
    k_tavg<<<dim3(8, NB), 256, 0, stream>>>(embh, embl, tavg);
    k_condfilm<<<dim3(NB), 256, 0, stream>>>(tavg, lin_w, lin_b, film_w, film_b, gbv);
    k_dist<<<dim3(63, 8), 256, 0, stream>>>(embh, embl, cbh, cbl, cbn, pmin, pidx);
    k_combine<<<dim3(32), 256, 0, stream>>>(pmin, pidx, codes);
    k_mod<<<dim3(2000), 256, 0, stream>>>(codes, cb, gbv, modh, modl);
    k_dec<<<dim3(63, 3), 256, 0, stream>>>(modh, modl, dwfh, dwfl, dec_b, out);
}

// Round 3
// 230.363 us; speedup vs baseline: 2.0998x; 1.3213x over previous
//
#include <hip/hip_runtime.h>

#define FR   8000
#define FRP  8064    // padded to 63*128
#define DD   512
#define CK   1024
#define KSZ  320
#define TT   500
#define NB   16

typedef unsigned int u32;
typedef unsigned short u16;
typedef __attribute__((ext_vector_type(8))) short b8;   // 8 x bf16 bits
typedef __attribute__((ext_vector_type(4))) float f4;

__device__ __forceinline__ float bf2f(u16 h) {
    u32 u = ((u32)h) << 16;
    return __builtin_bit_cast(float, u);
}
__device__ __forceinline__ u16 f2bf(float f) {  // RNE
    u32 u = __builtin_bit_cast(u32, f);
    u32 r = u + 0x7FFFu + ((u >> 16) & 1u);
    return (u16)(r >> 16);
}

__device__ __forceinline__ void gld16(const u16* g, u16* s) {
    __builtin_amdgcn_global_load_lds(
        (const __attribute__((address_space(1))) u32*)g,
        (__attribute__((address_space(3))) u32*)s, 16, 0, 0);
}

__device__ __forceinline__ f4 mfma(b8 a, b8 b, f4 c) {
    return __builtin_amdgcn_mfma_f32_16x16x32_bf16(a, b, c, 0, 0, 0);
}

__device__ __forceinline__ void split8(float4 a, float4 b, u16* dh, u16* dl) {
    float xs[8] = {a.x, a.y, a.z, a.w, b.x, b.y, b.z, b.w};
    union { u16 u[8]; b8 v; } H, L;
#pragma unroll
    for (int i = 0; i < 8; ++i) {
        u16 h = f2bf(xs[i]);
        H.u[i] = h;
        L.u[i] = f2bf(xs[i] - bf2f(h));
    }
    *(b8*)dh = H.v;
    *(b8*)dl = L.v;
}

// ---------------------------------------------------------------------------
// Merged prep: split enc_w [0,80), split cb [80,336), dwf [336,1104),
// cbnorm [1104,1136)
// ---------------------------------------------------------------------------
__global__ __launch_bounds__(256) void k_prep(const float* __restrict__ enc_w,
                                              u16* __restrict__ ewh, u16* __restrict__ ewl,
                                              const float* __restrict__ cb,
                                              u16* __restrict__ cbh, u16* __restrict__ cbl,
                                              const float* __restrict__ dw,
                                              u16* __restrict__ dwfh, u16* __restrict__ dwfl,
                                              float* __restrict__ cbn) {
    const int bid = blockIdx.x, tid = threadIdx.x;
    if (bid < 80) {
        int i = (bid * 256 + tid) * 8;
        float4 a = *(const float4*)&enc_w[i];
        float4 b = *(const float4*)&enc_w[i + 4];
        split8(a, b, &ewh[i], &ewl[i]);
    } else if (bid < 336) {
        int i = ((bid - 80) * 256 + tid) * 8;
        float4 a = *(const float4*)&cb[i];
        float4 b = *(const float4*)&cb[i + 4];
        split8(a, b, &cbh[i], &cbl[i]);
    } else if (bid < 1104) {
        int idx = (bid - 336) * 256 + tid;  // 384*512
        int s = idx >> 9, d = idx & 511;
        float v = (s < KSZ) ? dw[d * KSZ + (KSZ - 1) - s] : 0.f;
        u16 hi = f2bf(v);
        dwfh[idx] = hi;
        dwfl[idx] = f2bf(v - bf2f(hi));
    } else {
        int c = (bid - 1104) * 32 + (tid >> 3);
        int l = tid & 7;
        float s = 0.f;
        for (int j = l * 4; j < DD; j += 32) {
            float4 v = *(const float4*)&cb[c * DD + j];
            s += v.x * v.x + v.y * v.y + v.z * v.z + v.w * v.w;
        }
        s += __shfl_xor(s, 1);
        s += __shfl_xor(s, 2);
        s += __shfl_xor(s, 4);
        if (l == 0) cbn[c] = s;
    }
}

// ---------------------------------------------------------------------------
// Encoder MFMA GEMM, double-buffered: emb[f,d] = wav[f,:].enc_w[d,:] + eb[d]
// ---------------------------------------------------------------------------
__global__ __launch_bounds__(256, 2) void k_enc(const float* __restrict__ wav,
                                                const u16* __restrict__ Bhg,
                                                const u16* __restrict__ Blg,
                                                const float* __restrict__ eb,
                                                u16* __restrict__ embh,
                                                u16* __restrict__ embl) {
    __shared__ __align__(16) u16 Ah[2][4096], Al[2][4096], Bh[2][4096], Bl[2][4096];
    const int tid = threadIdx.x;
    const int l = tid & 63, w = tid >> 6, wm = w >> 1, wn = w & 1;
    const int lane16 = l & 15, laneK = l >> 4;
    const int f0 = blockIdx.x * 128, d0 = blockIdx.y * 128;

    const int p0 = w * 128 + l, p1 = p0 + 64;
    const int r0 = p0 >> 2, q0 = (p0 & 3) ^ ((r0 >> 1) & 3);
    const int r1 = p1 >> 2, q1 = (p1 & 3) ^ ((r1 >> 1) & 3);
    const u16* gB0h = Bhg + (size_t)(d0 + r0) * KSZ + q0 * 8;
    const u16* gB1h = Bhg + (size_t)(d0 + r1) * KSZ + q1 * 8;
    const u16* gB0l = Blg + (size_t)(d0 + r0) * KSZ + q0 * 8;
    const u16* gB1l = Blg + (size_t)(d0 + r1) * KSZ + q1 * 8;

    const int pa0 = tid, pa1 = tid + 256;
    const int ra0 = pa0 >> 2, qa0 = (pa0 & 3) ^ ((ra0 >> 1) & 3);
    const int ra1 = pa1 >> 2, qa1 = (pa1 & 3) ^ ((ra1 >> 1) & 3);
    int fr0 = f0 + ra0; if (fr0 > FR - 1) fr0 = FR - 1;
    int fr1 = f0 + ra1; if (fr1 > FR - 1) fr1 = FR - 1;
    const float* wv0 = wav + (size_t)fr0 * KSZ + qa0 * 8;
    const float* wv1 = wav + (size_t)fr1 * KSZ + qa1 * 8;

    int offA[4], offB[4];
#pragma unroll
    for (int i = 0; i < 4; ++i) {
        int ra = wm * 64 + i * 16 + lane16;
        offA[i] = (ra * 4 + (laneK ^ ((ra >> 1) & 3))) * 8;
        int rb = wn * 64 + i * 16 + lane16;
        offB[i] = (rb * 4 + (laneK ^ ((rb >> 1) & 3))) * 8;
    }

    f4 zero = {0.f, 0.f, 0.f, 0.f};
    f4 acc[4][4];
#pragma unroll
    for (int i = 0; i < 4; ++i)
#pragma unroll
        for (int j = 0; j < 4; ++j) acc[i][j] = zero;

    auto stgB = [&](int buf, int kt) {
        gld16(gB0h + kt, Bh[buf] + w * 1024);
        gld16(gB1h + kt, Bh[buf] + w * 1024 + 512);
        gld16(gB0l + kt, Bl[buf] + w * 1024);
        gld16(gB1l + kt, Bl[buf] + w * 1024 + 512);
    };
    auto wrA = [&](int buf, float4 x0, float4 x1, float4 y0, float4 y1) {
        split8(x0, x1, Ah[buf] + pa0 * 8, Al[buf] + pa0 * 8);
        split8(y0, y1, Ah[buf] + pa1 * 8, Al[buf] + pa1 * 8);
    };
    auto compute = [&](int buf) {
        b8 ah[4], al[4], bh[4], bl[4];
#pragma unroll
        for (int i = 0; i < 4; ++i) {
            ah[i] = *(const b8*)(Ah[buf] + offA[i]);
            al[i] = *(const b8*)(Al[buf] + offA[i]);
            bh[i] = *(const b8*)(Bh[buf] + offB[i]);
            bl[i] = *(const b8*)(Bl[buf] + offB[i]);
        }
#pragma unroll
        for (int mi = 0; mi < 4; ++mi)
#pragma unroll
            for (int ni = 0; ni < 4; ++ni) {
                acc[mi][ni] = mfma(ah[mi], bh[ni], acc[mi][ni]);
                acc[mi][ni] = mfma(ah[mi], bl[ni], acc[mi][ni]);
                acc[mi][ni] = mfma(al[mi], bh[ni], acc[mi][ni]);
            }
    };

    // prologue: stage tile 0
    stgB(0, 0);
    {
        float4 x0 = *(const float4*)(wv0);
        float4 x1 = *(const float4*)(wv0 + 4);
        float4 y0 = *(const float4*)(wv1);
        float4 y1 = *(const float4*)(wv1 + 4);
        wrA(0, x0, x1, y0, y1);
    }
    __syncthreads();
    int cur = 0;
    const int NT = KSZ / 32;  // 10
    for (int t = 0; t < NT - 1; ++t) {
        int kt = (t + 1) * 32;
        stgB(cur ^ 1, kt);
        float4 x0 = *(const float4*)(wv0 + kt);
        float4 x1 = *(const float4*)(wv0 + kt + 4);
        float4 y0 = *(const float4*)(wv1 + kt);
        float4 y1 = *(const float4*)(wv1 + kt + 4);
        compute(cur);
        wrA(cur ^ 1, x0, x1, y0, y1);
        __syncthreads();
        cur ^= 1;
    }
    compute(cur);

    float ebv[4];
#pragma unroll
    for (int ni = 0; ni < 4; ++ni) ebv[ni] = eb[d0 + wn * 64 + ni * 16 + lane16];
#pragma unroll
    for (int mi = 0; mi < 4; ++mi)
#pragma unroll
        for (int q = 0; q < 4; ++q) {
            int f = f0 + wm * 64 + mi * 16 + laneK * 4 + q;
#pragma unroll
            for (int ni = 0; ni < 4; ++ni) {
                int d = d0 + wn * 64 + ni * 16 + lane16;
                float v = acc[mi][ni][q] + ebv[ni];
                u16 h = f2bf(v);
                size_t o = (size_t)f * DD + d;
                embh[o] = h;
                embl[o] = f2bf(v - bf2f(h));
            }
        }
}

// ---------------------------------------------------------------------------
// time_avg from split emb
// ---------------------------------------------------------------------------
__global__ __launch_bounds__(256) void k_tavg(const u16* __restrict__ eh,
                                              const u16* __restrict__ el,
                                              float* __restrict__ tavg) {
    const int b = blockIdx.y;
    const int d0 = blockIdx.x * 64;
    const int dl = threadIdx.x & 63, tg = threadIdx.x >> 6;
    float s = 0.f;
    for (int t = tg; t < TT; t += 4) {
        size_t o = (size_t)(b * TT + t) * DD + d0 + dl;
        s += bf2f(eh[o]) + bf2f(el[o]);
    }
    __shared__ float red[4][64];
    red[tg][dl] = s;
    __syncthreads();
    if (tg == 0)
        tavg[b * DD + d0 + dl] =
            (red[0][dl] + red[1][dl] + red[2][dl] + red[3][dl]) * (1.0f / TT);
}

// ---------------------------------------------------------------------------
// cond[b,i] = tavg[b,:].lin_w[i,:] + lin_b[i]   — wave per row i, all b.
// Lane k-mapping: k = lane + 64*j (conflict-free LDS, coalesced weights).
// ---------------------------------------------------------------------------
__global__ __launch_bounds__(256) void k_cond(const float* __restrict__ tavg,
                                              const float* __restrict__ lw,
                                              const float* __restrict__ lb,
                                              float* __restrict__ cond) {
    __shared__ float stv[NB * DD];
    for (int i = threadIdx.x * 4; i < NB * DD; i += 1024)
        *(float4*)&stv[i] = *(const float4*)&tavg[i];
    __syncthreads();
    const int w = threadIdx.x >> 6, lane = threadIdx.x & 63;
    const int row = blockIdx.x * 4 + w;
    float wv[8];
#pragma unroll
    for (int j = 0; j < 8; ++j) wv[j] = lw[(size_t)row * DD + lane + 64 * j];
    float r[NB];
#pragma unroll
    for (int b = 0; b < NB; ++b) {
        float s = 0.f;
#pragma unroll
        for (int j = 0; j < 8; ++j) s += wv[j] * stv[b * DD + lane + 64 * j];
        r[b] = s;
    }
#pragma unroll
    for (int m = 32; m >= 1; m >>= 1)
#pragma unroll
        for (int b = 0; b < NB; ++b) r[b] += __shfl_xor(r[b], m);
    if (lane < NB) cond[lane * DD + row] = r[lane] + lb[row];
}

// ---------------------------------------------------------------------------
// gbv[b,o] = cond[b,:].film_w[o,:] + film_b[o]
// ---------------------------------------------------------------------------
__global__ __launch_bounds__(256) void k_film(const float* __restrict__ cond,
                                              const float* __restrict__ fw,
                                              const float* __restrict__ fb,
                                              float* __restrict__ gbv) {
    __shared__ float sc[NB * DD];
    for (int i = threadIdx.x * 4; i < NB * DD; i += 1024)
        *(float4*)&sc[i] = *(const float4*)&cond[i];
    __syncthreads();
    const int w = threadIdx.x >> 6, lane = threadIdx.x & 63;
    const int row = blockIdx.x * 4 + w;
    float wv[8];
#pragma unroll
    for (int j = 0; j < 8; ++j) wv[j] = fw[(size_t)row * DD + lane + 64 * j];
    float r[NB];
#pragma unroll
    for (int b = 0; b < NB; ++b) {
        float s = 0.f;
#pragma unroll
        for (int j = 0; j < 8; ++j) s += wv[j] * sc[b * DD + lane + 64 * j];
        r[b] = s;
    }
#pragma unroll
    for (int m = 32; m >= 1; m >>= 1)
#pragma unroll
        for (int b = 0; b < NB; ++b) r[b] += __shfl_xor(r[b], m);
    if (lane < NB) gbv[lane * 2 * DD + row] = r[lane] + fb[row];
}

// ---------------------------------------------------------------------------
// VQ dist MFMA (double-buffered) + fused per-block argmin.
// ---------------------------------------------------------------------------
__global__ __launch_bounds__(256, 2) void k_dist(const u16* __restrict__ Ahg,
                                                 const u16* __restrict__ Alg,
                                                 const u16* __restrict__ Bhg,
                                                 const u16* __restrict__ Blg,
                                                 const float* __restrict__ cbn,
                                                 float* __restrict__ pmin,
                                                 int* __restrict__ pidx) {
    __shared__ __align__(16) u16 Ah[2][4096], Al[2][4096], Bh[2][4096], Bl[2][4096];
    __shared__ float s_best[128][2];
    __shared__ int s_bidx[128][2];
    const int tid = threadIdx.x;
    const int l = tid & 63, w = tid >> 6, wm = w >> 1, wn = w & 1;
    const int lane16 = l & 15, laneK = l >> 4;
    const int f0 = blockIdx.x * 128, c0 = blockIdx.y * 128;

    const int p0 = w * 128 + l, p1 = p0 + 64;
    const int r0 = p0 >> 2, q0 = (p0 & 3) ^ ((r0 >> 1) & 3);
    const int r1 = p1 >> 2, q1 = (p1 & 3) ^ ((r1 >> 1) & 3);
    const u16* gA0h = Ahg + (size_t)(f0 + r0) * DD + q0 * 8;
    const u16* gA1h = Ahg + (size_t)(f0 + r1) * DD + q1 * 8;
    const u16* gA0l = Alg + (size_t)(f0 + r0) * DD + q0 * 8;
    const u16* gA1l = Alg + (size_t)(f0 + r1) * DD + q1 * 8;
    const u16* gB0h = Bhg + (size_t)(c0 + r0) * DD + q0 * 8;
    const u16* gB1h = Bhg + (size_t)(c0 + r1) * DD + q1 * 8;
    const u16* gB0l = Blg + (size_t)(c0 + r0) * DD + q0 * 8;
    const u16* gB1l = Blg + (size_t)(c0 + r1) * DD + q1 * 8;

    int offA[4], offB[4];
#pragma unroll
    for (int i = 0; i < 4; ++i) {
        int ra = wm * 64 + i * 16 + lane16;
        offA[i] = (ra * 4 + (laneK ^ ((ra >> 1) & 3))) * 8;
        int rb = wn * 64 + i * 16 + lane16;
        offB[i] = (rb * 4 + (laneK ^ ((rb >> 1) & 3))) * 8;
    }

    f4 zero = {0.f, 0.f, 0.f, 0.f};
    f4 acc[4][4];
#pragma unroll
    for (int i = 0; i < 4; ++i)
#pragma unroll
        for (int j = 0; j < 4; ++j) acc[i][j] = zero;

    auto stg = [&](int buf, int kt) {
        gld16(gA0h + kt, Ah[buf] + w * 1024);
        gld16(gA1h + kt, Ah[buf] + w * 1024 + 512);
        gld16(gA0l + kt, Al[buf] + w * 1024);
        gld16(gA1l + kt, Al[buf] + w * 1024 + 512);
        gld16(gB0h + kt, Bh[buf] + w * 1024);
        gld16(gB1h + kt, Bh[buf] + w * 1024 + 512);
        gld16(gB0l + kt, Bl[buf] + w * 1024);
        gld16(gB1l + kt, Bl[buf] + w * 1024 + 512);
    };
    auto compute = [&](int buf) {
        b8 ah[4], al[4], bh[4], bl[4];
#pragma unroll
        for (int i = 0; i < 4; ++i) {
            ah[i] = *(const b8*)(Ah[buf] + offA[i]);
            al[i] = *(const b8*)(Al[buf] + offA[i]);
            bh[i] = *(const b8*)(Bh[buf] + offB[i]);
            bl[i] = *(const b8*)(Bl[buf] + offB[i]);
        }
#pragma unroll
        for (int mi = 0; mi < 4; ++mi)
#pragma unroll
            for (int ni = 0; ni < 4; ++ni) {
                acc[mi][ni] = mfma(ah[mi], bh[ni], acc[mi][ni]);
                acc[mi][ni] = mfma(ah[mi], bl[ni], acc[mi][ni]);
                acc[mi][ni] = mfma(al[mi], bh[ni], acc[mi][ni]);
            }
    };

    stg(0, 0);
    __syncthreads();
    int cur = 0;
    const int NT = DD / 32;  // 16
    for (int t = 0; t < NT - 1; ++t) {
        stg(cur ^ 1, (t + 1) * 32);
        compute(cur);
        __syncthreads();
        cur ^= 1;
    }
    compute(cur);

    float cbv[4];
    int cidx[4];
#pragma unroll
    for (int ni = 0; ni < 4; ++ni) {
        cidx[ni] = c0 + wn * 64 + ni * 16 + lane16;
        cbv[ni] = cbn[cidx[ni]];
    }
#pragma unroll
    for (int mi = 0; mi < 4; ++mi)
#pragma unroll
        for (int q = 0; q < 4; ++q) {
            float best = 3.4e38f;
            int bi = 0x7fffffff;
#pragma unroll
            for (int ni = 0; ni < 4; ++ni) {
                float s = cbv[ni] - 2.0f * acc[mi][ni][q];
                if (s < best || (s == best && cidx[ni] < bi)) { best = s; bi = cidx[ni]; }
            }
#pragma unroll
            for (int m = 8; m >= 1; m >>= 1) {
                float os = __shfl_xor(best, m);
                int oi = __shfl_xor(bi, m);
                if (os < best || (os == best && oi < bi)) { best = os; bi = oi; }
            }
            if (lane16 == 0) {
                int rl = wm * 64 + mi * 16 + laneK * 4 + q;
                s_best[rl][wn] = best;
                s_bidx[rl][wn] = bi;
            }
        }
    __syncthreads();
    if (tid < 128) {
        float b0 = s_best[tid][0], b1 = s_best[tid][1];
        int i0 = s_bidx[tid][0], i1 = s_bidx[tid][1];
        bool t1 = (b1 < b0) || (b1 == b0 && i1 < i0);
        int f = f0 + tid;
        if (f < FR) {
            pmin[f * 8 + blockIdx.y] = t1 ? b1 : b0;
            pidx[f * 8 + blockIdx.y] = t1 ? i1 : i0;
        }
    }
}

__global__ void k_combine(const float* __restrict__ pmin,
                          const int* __restrict__ pidx,
                          int* __restrict__ codes) {
    int f = blockIdx.x * 256 + threadIdx.x;
    if (f < FR) {
        float best = pmin[f * 8];
        int bi = pidx[f * 8];
#pragma unroll
        for (int y = 1; y < 8; ++y) {
            float s = pmin[f * 8 + y];
            if (s < best) { best = s; bi = pidx[f * 8 + y]; }
        }
        codes[f] = bi;
    }
}

// ---------------------------------------------------------------------------
// modulated = gamma*cb[code] + beta, split to bf16 hi/lo
// ---------------------------------------------------------------------------
__global__ __launch_bounds__(256) void k_mod(const int* __restrict__ codes,
                                             const float* __restrict__ cb,
                                             const float* __restrict__ gbv,
                                             u16* __restrict__ mh,
                                             u16* __restrict__ ml) {
    int idx = blockIdx.x * 256 + threadIdx.x;  // 8000*64
    int f = idx >> 6, d = (idx & 63) * 8;
    int b = f / TT;
    int code = codes[f];
    const float* cp = cb + (size_t)code * DD + d;
    const float* gp = gbv + b * 2 * DD + d;
    const float* bp = gp + DD;
    union { u16 u[8]; b8 v; } H, L;
#pragma unroll
    for (int i = 0; i < 8; ++i) {
        float m = gp[i] * cp[i] + bp[i];
        u16 h = f2bf(m);
        H.u[i] = h;
        L.u[i] = f2bf(m - bf2f(h));
    }
    size_t o = (size_t)f * DD + d;
    *(b8*)&mh[o] = H.v;
    *(b8*)&ml[o] = L.v;
}

// ---------------------------------------------------------------------------
// Decoder MFMA GEMM (double-buffered): out[f*320+s] = mod[f,:].dwf[s,:] + db
// ---------------------------------------------------------------------------
__global__ __launch_bounds__(256, 2) void k_dec(const u16* __restrict__ Ahg,
                                                const u16* __restrict__ Alg,
                                                const u16* __restrict__ Bhg,
                                                const u16* __restrict__ Blg,
                                                const float* __restrict__ db,
                                                float* __restrict__ out) {
    __shared__ __align__(16) u16 Ah[2][4096], Al[2][4096], Bh[2][4096], Bl[2][4096];
    const int tid = threadIdx.x;
    const int l = tid & 63, w = tid >> 6, wm = w >> 1, wn = w & 1;
    const int lane16 = l & 15, laneK = l >> 4;
    const int f0 = blockIdx.x * 128, s0 = blockIdx.y * 128;

    const int p0 = w * 128 + l, p1 = p0 + 64;
    const int r0 = p0 >> 2, q0 = (p0 & 3) ^ ((r0 >> 1) & 3);
    const int r1 = p1 >> 2, q1 = (p1 & 3) ^ ((r1 >> 1) & 3);
    const u16* gA0h = Ahg + (size_t)(f0 + r0) * DD + q0 * 8;
    const u16* gA1h = Ahg + (size_t)(f0 + r1) * DD + q1 * 8;
    const u16* gA0l = Alg + (size_t)(f0 + r0) * DD + q0 * 8;
    const u16* gA1l = Alg + (size_t)(f0 + r1) * DD + q1 * 8;
    const u16* gB0h = Bhg + (size_t)(s0 + r0) * DD + q0 * 8;
    const u16* gB1h = Bhg + (size_t)(s0 + r1) * DD + q1 * 8;
    const u16* gB0l = Blg + (size_t)(s0 + r0) * DD + q0 * 8;
    const u16* gB1l = Blg + (size_t)(s0 + r1) * DD + q1 * 8;

    int offA[4], offB[4];
#pragma unroll
    for (int i = 0; i < 4; ++i) {
        int ra = wm * 64 + i * 16 + lane16;
        offA[i] = (ra * 4 + (laneK ^ ((ra >> 1) & 3))) * 8;
        int rb = wn * 64 + i * 16 + lane16;
        offB[i] = (rb * 4 + (laneK ^ ((rb >> 1) & 3))) * 8;
    }

    f4 zero = {0.f, 0.f, 0.f, 0.f};
    f4 acc[4][4];
#pragma unroll
    for (int i = 0; i < 4; ++i)
#pragma unroll
        for (int j = 0; j < 4; ++j) acc[i][j] = zero;

    auto stg = [&](int buf, int kt) {
        gld16(gA0h + kt, Ah[buf] + w * 1024);
        gld16(gA1h + kt, Ah[buf] + w * 1024 + 512);
        gld16(gA0l + kt, Al[buf] + w * 1024);
        gld16(gA1l + kt, Al[buf] + w * 1024 + 512);
        gld16(gB0h + kt, Bh[buf] + w * 1024);
        gld16(gB1h + kt, Bh[buf] + w * 1024 + 512);
        gld16(gB0l + kt, Bl[buf] + w * 1024);
        gld16(gB1l + kt, Bl[buf] + w * 1024 + 512);
    };
    auto compute = [&](int buf) {
        b8 ah[4], al[4], bh[4], bl[4];
#pragma unroll
        for (int i = 0; i < 4; ++i) {
            ah[i] = *(const b8*)(Ah[buf] + offA[i]);
            al[i] = *(const b8*)(Al[buf] + offA[i]);
            bh[i] = *(const b8*)(Bh[buf] + offB[i]);
            bl[i] = *(const b8*)(Bl[buf] + offB[i]);
        }
#pragma unroll
        for (int mi = 0; mi < 4; ++mi)
#pragma unroll
            for (int ni = 0; ni < 4; ++ni) {
                acc[mi][ni] = mfma(ah[mi], bh[ni], acc[mi][ni]);
                acc[mi][ni] = mfma(ah[mi], bl[ni], acc[mi][ni]);
                acc[mi][ni] = mfma(al[mi], bh[ni], acc[mi][ni]);
            }
    };

    stg(0, 0);
    __syncthreads();
    int cur = 0;
    const int NT = DD / 32;  // 16
    for (int t = 0; t < NT - 1; ++t) {
        stg(cur ^ 1, (t + 1) * 32);
        compute(cur);
        __syncthreads();
        cur ^= 1;
    }
    compute(cur);

    const float d0v = db[0];
#pragma unroll
    for (int mi = 0; mi < 4; ++mi)
#pragma unroll
        for (int q = 0; q < 4; ++q) {
            int f = f0 + wm * 64 + mi * 16 + laneK * 4 + q;
            if (f < FR) {
#pragma unroll
                for (int ni = 0; ni < 4; ++ni) {
                    int s = s0 + wn * 64 + ni * 16 + lane16;
                    if (s < KSZ) out[(size_t)f * KSZ + s] = acc[mi][ni][q] + d0v;
                }
            }
        }
}

// ---------------------------------------------------------------------------
extern "C" void kernel_launch(void* const* d_in, const int* in_sizes, int n_in,
                              void* d_out, int out_size, void* d_ws, size_t ws_size,
                              hipStream_t stream) {
    const float* wav    = (const float*)d_in[0];
    const float* enc_w  = (const float*)d_in[1];
    const float* enc_b  = (const float*)d_in[2];
    const float* cb     = (const float*)d_in[3];
    const float* lin_w  = (const float*)d_in[4];
    const float* lin_b  = (const float*)d_in[5];
    const float* film_w = (const float*)d_in[6];
    const float* film_b = (const float*)d_in[7];
    const float* dec_w  = (const float*)d_in[8];
    const float* dec_b  = (const float*)d_in[9];
    float* out = (float*)d_out;

    char* p = (char*)d_ws;
    u16* embh = (u16*)p;                 p += (size_t)FRP * DD * 2;
    u16* embl = (u16*)p;                 p += (size_t)FRP * DD * 2;
    u16* ewh  = (u16*)p;                 p += (size_t)DD * KSZ * 2;
    u16* ewl  = (u16*)p;                 p += (size_t)DD * KSZ * 2;
    u16* cbh  = (u16*)p;                 p += (size_t)CK * DD * 2;
    u16* cbl  = (u16*)p;                 p += (size_t)CK * DD * 2;
    u16* dwfh = (u16*)p;                 p += (size_t)384 * DD * 2;
    u16* dwfl = (u16*)p;                 p += (size_t)384 * DD * 2;
    float* cbn  = (float*)p;             p += CK * 4;
    float* tavg = (float*)p;             p += NB * DD * 4;
    float* cond = (float*)p;             p += NB * DD * 4;
    float* gbv  = (float*)p;             p += NB * 2 * DD * 4;
    float* pmin = (float*)p;             p += FR * 8 * 4;
    int*   pidx = (int*)p;               p += FR * 8 * 4;
    int*   codes = (int*)p;              p += FR * 4;
    u16* modh = embh;  // alias: emb dead after k_dist/k_tavg
    u16* modl = embl;

    k_prep<<<dim3(1136), 256, 0, stream>>>(enc_w, ewh, ewl, cb, cbh, cbl,
                                           dec_w, dwfh, dwfl, cbn);
    k_enc<<<dim3(63, 4), 256, 0, stream>>>(wav, ewh, ewl, enc_b, embh, embl);
    k_tavg<<<dim3(8, NB), 256, 0, stream>>>(embh, embl, tavg);
    k_cond<<<dim3(128), 256, 0, stream>>>(tavg, lin_w, lin_b, cond);
    k_film<<<dim3(256), 256, 0, stream>>>(cond, film_w, film_b, gbv);
    k_dist<<<dim3(63, 8), 256, 0, stream>>>(embh, embl, cbh, cbl, cbn, pmin, pidx);
    k_combine<<<dim3(32), 256, 0, stream>>>(pmin, pidx, codes);
    k_mod<<<dim3(2000), 256, 0, stream>>>(codes, cb, gbv, modh, modl);
    k_dec<<<dim3(63, 3), 256, 0, stream>>>(modh, modl, dwfh, dwfl, dec_b, out);
}

// Round 4
// 188.072 us; speedup vs baseline: 2.5719x; 1.2249x over previous
//
#include <hip/hip_runtime.h>

#define FR   8000
#define FRP  8192    // padded to 64*128 for XCD-chunked dist mapping
#define DD   512
#define CK   1024
#define KSZ  320
#define TT   500
#define NB   16

typedef unsigned int u32;
typedef unsigned short u16;
typedef __attribute__((ext_vector_type(8))) short b8;   // 8 x bf16 bits
typedef __attribute__((ext_vector_type(4))) float f4;

__device__ __forceinline__ float bf2f(u16 h) {
    u32 u = ((u32)h) << 16;
    return __builtin_bit_cast(float, u);
}
__device__ __forceinline__ u16 f2bf(float f) {  // RNE
    u32 u = __builtin_bit_cast(u32, f);
    u32 r = u + 0x7FFFu + ((u >> 16) & 1u);
    return (u16)(r >> 16);
}

__device__ __forceinline__ void gld16(const u16* g, u16* s) {
    __builtin_amdgcn_global_load_lds(
        (const __attribute__((address_space(1))) u32*)g,
        (__attribute__((address_space(3))) u32*)s, 16, 0, 0);
}

__device__ __forceinline__ f4 mfma(b8 a, b8 b, f4 c) {
    return __builtin_amdgcn_mfma_f32_16x16x32_bf16(a, b, c, 0, 0, 0);
}

__device__ __forceinline__ void split8(float4 a, float4 b, u16* dh, u16* dl) {
    float xs[8] = {a.x, a.y, a.z, a.w, b.x, b.y, b.z, b.w};
    union { u16 u[8]; b8 v; } H, L;
#pragma unroll
    for (int i = 0; i < 8; ++i) {
        u16 h = f2bf(xs[i]);
        H.u[i] = h;
        L.u[i] = f2bf(xs[i] - bf2f(h));
    }
    *(b8*)dh = H.v;
    *(b8*)dl = L.v;
}

// ---------------------------------------------------------------------------
// Merged prep: split enc_w [0,80), split cb [80,336), dwf [336,1104),
// cbnorm [1104,1136), split wav [1136,2386)
// ---------------------------------------------------------------------------
__global__ __launch_bounds__(256) void k_prep(const float* __restrict__ enc_w,
                                              u16* __restrict__ ewh, u16* __restrict__ ewl,
                                              const float* __restrict__ cb,
                                              u16* __restrict__ cbh, u16* __restrict__ cbl,
                                              const float* __restrict__ dw,
                                              u16* __restrict__ dwfh, u16* __restrict__ dwfl,
                                              float* __restrict__ cbn,
                                              const float* __restrict__ wav,
                                              u16* __restrict__ wavh, u16* __restrict__ wavl) {
    const int bid = blockIdx.x, tid = threadIdx.x;
    if (bid < 80) {
        int i = (bid * 256 + tid) * 8;
        float4 a = *(const float4*)&enc_w[i];
        float4 b = *(const float4*)&enc_w[i + 4];
        split8(a, b, &ewh[i], &ewl[i]);
    } else if (bid < 336) {
        int i = ((bid - 80) * 256 + tid) * 8;
        float4 a = *(const float4*)&cb[i];
        float4 b = *(const float4*)&cb[i + 4];
        split8(a, b, &cbh[i], &cbl[i]);
    } else if (bid < 1104) {
        int idx = (bid - 336) * 256 + tid;  // 384*512
        int s = idx >> 9, d = idx & 511;
        float v = (s < KSZ) ? dw[d * KSZ + (KSZ - 1) - s] : 0.f;
        u16 hi = f2bf(v);
        dwfh[idx] = hi;
        dwfl[idx] = f2bf(v - bf2f(hi));
    } else if (bid < 1136) {
        int c = (bid - 1104) * 32 + (tid >> 3);
        int l = tid & 7;
        float s = 0.f;
        for (int j = l * 4; j < DD; j += 32) {
            float4 v = *(const float4*)&cb[c * DD + j];
            s += v.x * v.x + v.y * v.y + v.z * v.z + v.w * v.w;
        }
        s += __shfl_xor(s, 1);
        s += __shfl_xor(s, 2);
        s += __shfl_xor(s, 4);
        if (l == 0) cbn[c] = s;
    } else {
        int i = ((bid - 1136) * 256 + tid) * 8;  // 2,560,000 = FR*KSZ
        float4 a = *(const float4*)&wav[i];
        float4 b = *(const float4*)&wav[i + 4];
        split8(a, b, &wavh[i], &wavl[i]);
    }
}

// Counted-vmcnt double-buffered pipeline shared structure (T3+T4):
//   stg(0,k0); stg(1,k1);
//   loop: vmcnt(8|0); barrier; compute(cur); barrier; stg(cur, t+2); flip
#define PIPELINE(NT, STRIDE)                                                  \
    stg(0, 0);                                                                \
    stg(1, STRIDE);                                                           \
    int cur = 0;                                                              \
    for (int t = 0; t < NT; ++t) {                                            \
        if (t < NT - 1) asm volatile("s_waitcnt vmcnt(8)" ::: "memory");      \
        else            asm volatile("s_waitcnt vmcnt(0)" ::: "memory");      \
        __builtin_amdgcn_s_barrier();                                         \
        asm volatile("" ::: "memory");                                        \
        compute(cur);                                                         \
        asm volatile("" ::: "memory");                                        \
        __builtin_amdgcn_s_barrier();                                         \
        if (t < NT - 2) stg(cur, (t + 2) * STRIDE);                           \
        cur ^= 1;                                                             \
    }

// ---------------------------------------------------------------------------
// Encoder MFMA GEMM: emb[f,d] = wav[f,:].enc_w[d,:] + eb[d]
// Grid 256 (1D, XCD-chunked): 64 f-panels x 4 d-panels.
// ---------------------------------------------------------------------------
__global__ __launch_bounds__(256, 2) void k_enc(const u16* __restrict__ Ahg,
                                                const u16* __restrict__ Alg,
                                                const u16* __restrict__ Bhg,
                                                const u16* __restrict__ Blg,
                                                const float* __restrict__ eb,
                                                u16* __restrict__ embh,
                                                u16* __restrict__ embl) {
    __shared__ __align__(16) u16 Ah[2][4096], Al[2][4096], Bh[2][4096], Bl[2][4096];
    const int tid = threadIdx.x;
    const int l = tid & 63, w = tid >> 6, wm = w >> 1, wn = w & 1;
    const int lane16 = l & 15, laneK = l >> 4;
    const int g = blockIdx.x;
    const int xcd = g & 7, slot = g >> 3;
    const int f0 = (xcd * 8 + (slot & 7)) * 128;
    const int d0 = (slot >> 3) * 128;

    const int p0 = w * 128 + l, p1 = p0 + 64;
    const int r0 = p0 >> 2, q0 = (p0 & 3) ^ ((r0 >> 1) & 3);
    const int r1 = p1 >> 2, q1 = (p1 & 3) ^ ((r1 >> 1) & 3);
    int fa0 = f0 + r0; if (fa0 > FR - 1) fa0 = FR - 1;
    int fa1 = f0 + r1; if (fa1 > FR - 1) fa1 = FR - 1;
    const u16* gA0h = Ahg + (size_t)fa0 * KSZ + q0 * 8;
    const u16* gA1h = Ahg + (size_t)fa1 * KSZ + q1 * 8;
    const u16* gA0l = Alg + (size_t)fa0 * KSZ + q0 * 8;
    const u16* gA1l = Alg + (size_t)fa1 * KSZ + q1 * 8;
    const u16* gB0h = Bhg + (size_t)(d0 + r0) * KSZ + q0 * 8;
    const u16* gB1h = Bhg + (size_t)(d0 + r1) * KSZ + q1 * 8;
    const u16* gB0l = Blg + (size_t)(d0 + r0) * KSZ + q0 * 8;
    const u16* gB1l = Blg + (size_t)(d0 + r1) * KSZ + q1 * 8;

    int offA[4], offB[4];
#pragma unroll
    for (int i = 0; i < 4; ++i) {
        int ra = wm * 64 + i * 16 + lane16;
        offA[i] = (ra * 4 + (laneK ^ ((ra >> 1) & 3))) * 8;
        int rb = wn * 64 + i * 16 + lane16;
        offB[i] = (rb * 4 + (laneK ^ ((rb >> 1) & 3))) * 8;
    }

    f4 zero = {0.f, 0.f, 0.f, 0.f};
    f4 acc[4][4];
#pragma unroll
    for (int i = 0; i < 4; ++i)
#pragma unroll
        for (int j = 0; j < 4; ++j) acc[i][j] = zero;

    auto stg = [&](int buf, int kt) {
        gld16(gA0h + kt, Ah[buf] + w * 1024);
        gld16(gA1h + kt, Ah[buf] + w * 1024 + 512);
        gld16(gA0l + kt, Al[buf] + w * 1024);
        gld16(gA1l + kt, Al[buf] + w * 1024 + 512);
        gld16(gB0h + kt, Bh[buf] + w * 1024);
        gld16(gB1h + kt, Bh[buf] + w * 1024 + 512);
        gld16(gB0l + kt, Bl[buf] + w * 1024);
        gld16(gB1l + kt, Bl[buf] + w * 1024 + 512);
    };
    auto compute = [&](int buf) {
        b8 ah[4], al[4], bh[4], bl[4];
#pragma unroll
        for (int i = 0; i < 4; ++i) {
            ah[i] = *(const b8*)(Ah[buf] + offA[i]);
            al[i] = *(const b8*)(Al[buf] + offA[i]);
            bh[i] = *(const b8*)(Bh[buf] + offB[i]);
            bl[i] = *(const b8*)(Bl[buf] + offB[i]);
        }
#pragma unroll
        for (int mi = 0; mi < 4; ++mi)
#pragma unroll
            for (int ni = 0; ni < 4; ++ni) {
                acc[mi][ni] = mfma(ah[mi], bh[ni], acc[mi][ni]);
                acc[mi][ni] = mfma(ah[mi], bl[ni], acc[mi][ni]);
                acc[mi][ni] = mfma(al[mi], bh[ni], acc[mi][ni]);
            }
    };

    PIPELINE(10, 32)

    float ebv[4];
#pragma unroll
    for (int ni = 0; ni < 4; ++ni) ebv[ni] = eb[d0 + wn * 64 + ni * 16 + lane16];
#pragma unroll
    for (int mi = 0; mi < 4; ++mi)
#pragma unroll
        for (int q = 0; q < 4; ++q) {
            int f = f0 + wm * 64 + mi * 16 + laneK * 4 + q;
#pragma unroll
            for (int ni = 0; ni < 4; ++ni) {
                int d = d0 + wn * 64 + ni * 16 + lane16;
                float v = acc[mi][ni][q] + ebv[ni];
                u16 h = f2bf(v);
                size_t o = (size_t)f * DD + d;
                embh[o] = h;
                embl[o] = f2bf(v - bf2f(h));
            }
        }
}

// ---------------------------------------------------------------------------
// time_avg, vectorized b8 loads
// ---------------------------------------------------------------------------
__global__ __launch_bounds__(256) void k_tavg(const u16* __restrict__ eh,
                                              const u16* __restrict__ el,
                                              float* __restrict__ tavg) {
    const int b = blockIdx.y, d0 = blockIdx.x * 64;
    const int dt = threadIdx.x & 7, tg = threadIdx.x >> 3;  // tg 0..31
    const int d = d0 + dt * 8;
    float s[8] = {};
    for (int t = tg; t < TT; t += 32) {
        size_t o = (size_t)(b * TT + t) * DD + d;
        b8 h = *(const b8*)(eh + o);
        b8 lo = *(const b8*)(el + o);
#pragma unroll
        for (int j = 0; j < 8; ++j) s[j] += bf2f((u16)h[j]) + bf2f((u16)lo[j]);
    }
#pragma unroll
    for (int m = 8; m <= 32; m <<= 1)
#pragma unroll
        for (int j = 0; j < 8; ++j) s[j] += __shfl_xor(s[j], m);
    __shared__ float red[4][64];
    const int w = threadIdx.x >> 6;
    if ((threadIdx.x & 63) < 8)
#pragma unroll
        for (int j = 0; j < 8; ++j) red[w][dt * 8 + j] = s[j];
    __syncthreads();
    if (threadIdx.x < 64)
        tavg[b * DD + d0 + threadIdx.x] =
            (red[0][threadIdx.x] + red[1][threadIdx.x] +
             red[2][threadIdx.x] + red[3][threadIdx.x]) * (1.0f / TT);
}

// ---------------------------------------------------------------------------
// cond[b,i] = tavg[b,:].lin_w[i,:] + lin_b[i]   — wave per row i, all b.
// ---------------------------------------------------------------------------
__global__ __launch_bounds__(256) void k_cond(const float* __restrict__ tavg,
                                              const float* __restrict__ lw,
                                              const float* __restrict__ lb,
                                              float* __restrict__ cond) {
    __shared__ float stv[NB * DD];
    for (int i = threadIdx.x * 4; i < NB * DD; i += 1024)
        *(float4*)&stv[i] = *(const float4*)&tavg[i];
    __syncthreads();
    const int w = threadIdx.x >> 6, lane = threadIdx.x & 63;
    const int row = blockIdx.x * 4 + w;
    float wv[8];
#pragma unroll
    for (int j = 0; j < 8; ++j) wv[j] = lw[(size_t)row * DD + lane + 64 * j];
    float r[NB];
#pragma unroll
    for (int b = 0; b < NB; ++b) {
        float s = 0.f;
#pragma unroll
        for (int j = 0; j < 8; ++j) s += wv[j] * stv[b * DD + lane + 64 * j];
        r[b] = s;
    }
#pragma unroll
    for (int m = 32; m >= 1; m >>= 1)
#pragma unroll
        for (int b = 0; b < NB; ++b) r[b] += __shfl_xor(r[b], m);
    if (lane < NB) cond[lane * DD + row] = r[lane] + lb[row];
}

__global__ __launch_bounds__(256) void k_film(const float* __restrict__ cond,
                                              const float* __restrict__ fw,
                                              const float* __restrict__ fb,
                                              float* __restrict__ gbv) {
    __shared__ float sc[NB * DD];
    for (int i = threadIdx.x * 4; i < NB * DD; i += 1024)
        *(float4*)&sc[i] = *(const float4*)&cond[i];
    __syncthreads();
    const int w = threadIdx.x >> 6, lane = threadIdx.x & 63;
    const int row = blockIdx.x * 4 + w;
    float wv[8];
#pragma unroll
    for (int j = 0; j < 8; ++j) wv[j] = fw[(size_t)row * DD + lane + 64 * j];
    float r[NB];
#pragma unroll
    for (int b = 0; b < NB; ++b) {
        float s = 0.f;
#pragma unroll
        for (int j = 0; j < 8; ++j) s += wv[j] * sc[b * DD + lane + 64 * j];
        r[b] = s;
    }
#pragma unroll
    for (int m = 32; m >= 1; m >>= 1)
#pragma unroll
        for (int b = 0; b < NB; ++b) r[b] += __shfl_xor(r[b], m);
    if (lane < NB) gbv[lane * 2 * DD + row] = r[lane] + fb[row];
}

// ---------------------------------------------------------------------------
// VQ dist MFMA + fused per-block argmin. Grid 512 (1D, XCD-chunked):
// each XCD gets 8 f-panels x all 8 c-panels (A 2MB + B 2MB = L2-resident).
// ---------------------------------------------------------------------------
__global__ __launch_bounds__(256, 2) void k_dist(const u16* __restrict__ Ahg,
                                                 const u16* __restrict__ Alg,
                                                 const u16* __restrict__ Bhg,
                                                 const u16* __restrict__ Blg,
                                                 const float* __restrict__ cbn,
                                                 float* __restrict__ pmin,
                                                 int* __restrict__ pidx) {
    __shared__ __align__(16) u16 Ah[2][4096], Al[2][4096], Bh[2][4096], Bl[2][4096];
    __shared__ float s_best[128][2];
    __shared__ int s_bidx[128][2];
    const int tid = threadIdx.x;
    const int l = tid & 63, w = tid >> 6, wm = w >> 1, wn = w & 1;
    const int lane16 = l & 15, laneK = l >> 4;
    const int g = blockIdx.x;
    const int xcd = g & 7, slot = g >> 3;
    const int f0 = (xcd * 8 + (slot & 7)) * 128;
    const int c0 = (slot >> 3) * 128;
    const int cy = slot >> 3;

    const int p0 = w * 128 + l, p1 = p0 + 64;
    const int r0 = p0 >> 2, q0 = (p0 & 3) ^ ((r0 >> 1) & 3);
    const int r1 = p1 >> 2, q1 = (p1 & 3) ^ ((r1 >> 1) & 3);
    const u16* gA0h = Ahg + (size_t)(f0 + r0) * DD + q0 * 8;
    const u16* gA1h = Ahg + (size_t)(f0 + r1) * DD + q1 * 8;
    const u16* gA0l = Alg + (size_t)(f0 + r0) * DD + q0 * 8;
    const u16* gA1l = Alg + (size_t)(f0 + r1) * DD + q1 * 8;
    const u16* gB0h = Bhg + (size_t)(c0 + r0) * DD + q0 * 8;
    const u16* gB1h = Bhg + (size_t)(c0 + r1) * DD + q1 * 8;
    const u16* gB0l = Blg + (size_t)(c0 + r0) * DD + q0 * 8;
    const u16* gB1l = Blg + (size_t)(c0 + r1) * DD + q1 * 8;

    int offA[4], offB[4];
#pragma unroll
    for (int i = 0; i < 4; ++i) {
        int ra = wm * 64 + i * 16 + lane16;
        offA[i] = (ra * 4 + (laneK ^ ((ra >> 1) & 3))) * 8;
        int rb = wn * 64 + i * 16 + lane16;
        offB[i] = (rb * 4 + (laneK ^ ((rb >> 1) & 3))) * 8;
    }

    f4 zero = {0.f, 0.f, 0.f, 0.f};
    f4 acc[4][4];
#pragma unroll
    for (int i = 0; i < 4; ++i)
#pragma unroll
        for (int j = 0; j < 4; ++j) acc[i][j] = zero;

    auto stg = [&](int buf, int kt) {
        gld16(gA0h + kt, Ah[buf] + w * 1024);
        gld16(gA1h + kt, Ah[buf] + w * 1024 + 512);
        gld16(gA0l + kt, Al[buf] + w * 1024);
        gld16(gA1l + kt, Al[buf] + w * 1024 + 512);
        gld16(gB0h + kt, Bh[buf] + w * 1024);
        gld16(gB1h + kt, Bh[buf] + w * 1024 + 512);
        gld16(gB0l + kt, Bl[buf] + w * 1024);
        gld16(gB1l + kt, Bl[buf] + w * 1024 + 512);
    };
    auto compute = [&](int buf) {
        b8 ah[4], al[4], bh[4], bl[4];
#pragma unroll
        for (int i = 0; i < 4; ++i) {
            ah[i] = *(const b8*)(Ah[buf] + offA[i]);
            al[i] = *(const b8*)(Al[buf] + offA[i]);
            bh[i] = *(const b8*)(Bh[buf] + offB[i]);
            bl[i] = *(const b8*)(Bl[buf] + offB[i]);
        }
#pragma unroll
        for (int mi = 0; mi < 4; ++mi)
#pragma unroll
            for (int ni = 0; ni < 4; ++ni) {
                acc[mi][ni] = mfma(ah[mi], bh[ni], acc[mi][ni]);
                acc[mi][ni] = mfma(ah[mi], bl[ni], acc[mi][ni]);
                acc[mi][ni] = mfma(al[mi], bh[ni], acc[mi][ni]);
            }
    };

    PIPELINE(16, 32)

    float cbv[4];
    int cidx[4];
#pragma unroll
    for (int ni = 0; ni < 4; ++ni) {
        cidx[ni] = c0 + wn * 64 + ni * 16 + lane16;
        cbv[ni] = cbn[cidx[ni]];
    }
#pragma unroll
    for (int mi = 0; mi < 4; ++mi)
#pragma unroll
        for (int q = 0; q < 4; ++q) {
            float best = 3.4e38f;
            int bi = 0x7fffffff;
#pragma unroll
            for (int ni = 0; ni < 4; ++ni) {
                float s = cbv[ni] - 2.0f * acc[mi][ni][q];
                if (s < best || (s == best && cidx[ni] < bi)) { best = s; bi = cidx[ni]; }
            }
#pragma unroll
            for (int m = 8; m >= 1; m >>= 1) {
                float os = __shfl_xor(best, m);
                int oi = __shfl_xor(bi, m);
                if (os < best || (os == best && oi < bi)) { best = os; bi = oi; }
            }
            if (lane16 == 0) {
                int rl = wm * 64 + mi * 16 + laneK * 4 + q;
                s_best[rl][wn] = best;
                s_bidx[rl][wn] = bi;
            }
        }
    __syncthreads();
    if (tid < 128) {
        float b0 = s_best[tid][0], b1 = s_best[tid][1];
        int i0 = s_bidx[tid][0], i1 = s_bidx[tid][1];
        bool t1 = (b1 < b0) || (b1 == b0 && i1 < i0);
        int f = f0 + tid;
        if (f < FR) {
            pmin[f * 8 + cy] = t1 ? b1 : b0;
            pidx[f * 8 + cy] = t1 ? i1 : i0;
        }
    }
}

// ---------------------------------------------------------------------------
// combine (inline) + modulated = gamma*cb[code] + beta, split to bf16 hi/lo
// ---------------------------------------------------------------------------
__global__ __launch_bounds__(256) void k_mod(const float* __restrict__ pmin,
                                             const int* __restrict__ pidx,
                                             const float* __restrict__ cb,
                                             const float* __restrict__ gbv,
                                             u16* __restrict__ mh,
                                             u16* __restrict__ ml) {
    int idx = blockIdx.x * 256 + threadIdx.x;  // 8000*64
    int f = idx >> 6, d = (idx & 63) * 8;
    int lane = threadIdx.x & 63;
    int code = 0;
    if (lane == 0) {
        float best = pmin[f * 8];
        code = pidx[f * 8];
#pragma unroll
        for (int y = 1; y < 8; ++y) {
            float s = pmin[f * 8 + y];
            if (s < best) { best = s; code = pidx[f * 8 + y]; }
        }
    }
    code = __shfl(code, 0);
    int b = f / TT;
    const float* cp = cb + (size_t)code * DD + d;
    const float* gp = gbv + b * 2 * DD + d;
    const float* bp = gp + DD;
    union { u16 u[8]; b8 v; } H, L;
#pragma unroll
    for (int i = 0; i < 8; ++i) {
        float m = gp[i] * cp[i] + bp[i];
        u16 h = f2bf(m);
        H.u[i] = h;
        L.u[i] = f2bf(m - bf2f(h));
    }
    size_t o = (size_t)f * DD + d;
    *(b8*)&mh[o] = H.v;
    *(b8*)&ml[o] = L.v;
}

// ---------------------------------------------------------------------------
// Decoder MFMA GEMM: out[f*320+s] = mod[f,:].dwf[s,:] + db
// Grid (3, 63): x = s-panel (fastest) so consecutive blocks share A panel.
// ---------------------------------------------------------------------------
__global__ __launch_bounds__(256, 2) void k_dec(const u16* __restrict__ Ahg,
                                                const u16* __restrict__ Alg,
                                                const u16* __restrict__ Bhg,
                                                const u16* __restrict__ Blg,
                                                const float* __restrict__ db,
                                                float* __restrict__ out) {
    __shared__ __align__(16) u16 Ah[2][4096], Al[2][4096], Bh[2][4096], Bl[2][4096];
    const int tid = threadIdx.x;
    const int l = tid & 63, w = tid >> 6, wm = w >> 1, wn = w & 1;
    const int lane16 = l & 15, laneK = l >> 4;
    const int f0 = blockIdx.y * 128, s0 = blockIdx.x * 128;

    const int p0 = w * 128 + l, p1 = p0 + 64;
    const int r0 = p0 >> 2, q0 = (p0 & 3) ^ ((r0 >> 1) & 3);
    const int r1 = p1 >> 2, q1 = (p1 & 3) ^ ((r1 >> 1) & 3);
    const u16* gA0h = Ahg + (size_t)(f0 + r0) * DD + q0 * 8;
    const u16* gA1h = Ahg + (size_t)(f0 + r1) * DD + q1 * 8;
    const u16* gA0l = Alg + (size_t)(f0 + r0) * DD + q0 * 8;
    const u16* gA1l = Alg + (size_t)(f0 + r1) * DD + q1 * 8;
    const u16* gB0h = Bhg + (size_t)(s0 + r0) * DD + q0 * 8;
    const u16* gB1h = Bhg + (size_t)(s0 + r1) * DD + q1 * 8;
    const u16* gB0l = Blg + (size_t)(s0 + r0) * DD + q0 * 8;
    const u16* gB1l = Blg + (size_t)(s0 + r1) * DD + q1 * 8;

    int offA[4], offB[4];
#pragma unroll
    for (int i = 0; i < 4; ++i) {
        int ra = wm * 64 + i * 16 + lane16;
        offA[i] = (ra * 4 + (laneK ^ ((ra >> 1) & 3))) * 8;
        int rb = wn * 64 + i * 16 + lane16;
        offB[i] = (rb * 4 + (laneK ^ ((rb >> 1) & 3))) * 8;
    }

    f4 zero = {0.f, 0.f, 0.f, 0.f};
    f4 acc[4][4];
#pragma unroll
    for (int i = 0; i < 4; ++i)
#pragma unroll
        for (int j = 0; j < 4; ++j) acc[i][j] = zero;

    auto stg = [&](int buf, int kt) {
        gld16(gA0h + kt, Ah[buf] + w * 1024);
        gld16(gA1h + kt, Ah[buf] + w * 1024 + 512);
        gld16(gA0l + kt, Al[buf] + w * 1024);
        gld16(gA1l + kt, Al[buf] + w * 1024 + 512);
        gld16(gB0h + kt, Bh[buf] + w * 1024);
        gld16(gB1h + kt, Bh[buf] + w * 1024 + 512);
        gld16(gB0l + kt, Bl[buf] + w * 1024);
        gld16(gB1l + kt, Bl[buf] + w * 1024 + 512);
    };
    auto compute = [&](int buf) {
        b8 ah[4], al[4], bh[4], bl[4];
#pragma unroll
        for (int i = 0; i < 4; ++i) {
            ah[i] = *(const b8*)(Ah[buf] + offA[i]);
            al[i] = *(const b8*)(Al[buf] + offA[i]);
            bh[i] = *(const b8*)(Bh[buf] + offB[i]);
            bl[i] = *(const b8*)(Bl[buf] + offB[i]);
        }
#pragma unroll
        for (int mi = 0; mi < 4; ++mi)
#pragma unroll
            for (int ni = 0; ni < 4; ++ni) {
                acc[mi][ni] = mfma(ah[mi], bh[ni], acc[mi][ni]);
                acc[mi][ni] = mfma(ah[mi], bl[ni], acc[mi][ni]);
                acc[mi][ni] = mfma(al[mi], bh[ni], acc[mi][ni]);
            }
    };

    PIPELINE(16, 32)

    const float d0v = db[0];
#pragma unroll
    for (int mi = 0; mi < 4; ++mi)
#pragma unroll
        for (int q = 0; q < 4; ++q) {
            int f = f0 + wm * 64 + mi * 16 + laneK * 4 + q;
            if (f < FR) {
#pragma unroll
                for (int ni = 0; ni < 4; ++ni) {
                    int s = s0 + wn * 64 + ni * 16 + lane16;
                    if (s < KSZ) out[(size_t)f * KSZ + s] = acc[mi][ni][q] + d0v;
                }
            }
        }
}

// ---------------------------------------------------------------------------
extern "C" void kernel_launch(void* const* d_in, const int* in_sizes, int n_in,
                              void* d_out, int out_size, void* d_ws, size_t ws_size,
                              hipStream_t stream) {
    const float* wav    = (const float*)d_in[0];
    const float* enc_w  = (const float*)d_in[1];
    const float* enc_b  = (const float*)d_in[2];
    const float* cb     = (const float*)d_in[3];
    const float* lin_w  = (const float*)d_in[4];
    const float* lin_b  = (const float*)d_in[5];
    const float* film_w = (const float*)d_in[6];
    const float* film_b = (const float*)d_in[7];
    const float* dec_w  = (const float*)d_in[8];
    const float* dec_b  = (const float*)d_in[9];
    float* out = (float*)d_out;

    char* p = (char*)d_ws;
    u16* embh = (u16*)p;                 p += (size_t)FRP * DD * 2;   // 8.4MB
    u16* embl = (u16*)p;                 p += (size_t)FRP * DD * 2;
    u16* wavh = (u16*)p;                 p += (size_t)FR * KSZ * 2;   // 5.1MB
    u16* wavl = (u16*)p;                 p += (size_t)FR * KSZ * 2;
    u16* ewh  = (u16*)p;                 p += (size_t)DD * KSZ * 2;
    u16* ewl  = (u16*)p;                 p += (size_t)DD * KSZ * 2;
    u16* cbh  = (u16*)p;                 p += (size_t)CK * DD * 2;
    u16* cbl  = (u16*)p;                 p += (size_t)CK * DD * 2;
    u16* dwfh = (u16*)p;                 p += (size_t)384 * DD * 2;
    u16* dwfl = (u16*)p;                 p += (size_t)384 * DD * 2;
    float* cbn  = (float*)p;             p += CK * 4;
    float* tavg = (float*)p;             p += NB * DD * 4;
    float* cond = (float*)p;             p += NB * DD * 4;
    float* gbv  = (float*)p;             p += NB * 2 * DD * 4;
    float* pmin = (float*)p;             p += FR * 8 * 4;
    int*   pidx = (int*)p;               p += FR * 8 * 4;
    u16* modh = embh;  // alias: emb dead after k_dist/k_tavg
    u16* modl = embl;

    k_prep<<<dim3(2386), 256, 0, stream>>>(enc_w, ewh, ewl, cb, cbh, cbl,
                                           dec_w, dwfh, dwfl, cbn, wav, wavh, wavl);
    k_enc<<<dim3(256), 256, 0, stream>>>(wavh, wavl, ewh, ewl, enc_b, embh, embl);
    k_tavg<<<dim3(8, NB), 256, 0, stream>>>(embh, embl, tavg);
    k_cond<<<dim3(128), 256, 0, stream>>>(tavg, lin_w, lin_b, cond);
    k_film<<<dim3(256), 256, 0, stream>>>(cond, film_w, film_b, gbv);
    k_dist<<<dim3(512), 256, 0, stream>>>(embh, embl, cbh, cbl, cbn, pmin, pidx);
    k_mod<<<dim3(2000), 256, 0, stream>>>(pmin, pidx, cb, gbv, modh, modl);
    k_dec<<<dim3(3, 63), 256, 0, stream>>>(modh, modl, dwfh, dwfl, dec_b, out);
}

// Round 6
// 180.203 us; speedup vs baseline: 2.6842x; 1.0437x over previous
//
#include <hip/hip_runtime.h>

#define FR   8000
#define FRP  8192    // padded to 64*128 for XCD-chunked dist mapping
#define DD   512
#define CK   1024
#define KSZ  320
#define TT   500
#define NB   16

typedef unsigned int u32;
typedef unsigned short u16;
typedef __attribute__((ext_vector_type(8))) short b8;   // 8 x bf16 bits
typedef __attribute__((ext_vector_type(4))) float f4;

__device__ __forceinline__ float bf2f(u16 h) {
    u32 u = ((u32)h) << 16;
    return __builtin_bit_cast(float, u);
}
__device__ __forceinline__ u16 f2bf(float f) {  // RNE
    u32 u = __builtin_bit_cast(u32, f);
    u32 r = u + 0x7FFFu + ((u >> 16) & 1u);
    return (u16)(r >> 16);
}

__device__ __forceinline__ void gld16(const u16* g, u16* s) {
    __builtin_amdgcn_global_load_lds(
        (const __attribute__((address_space(1))) u32*)g,
        (__attribute__((address_space(3))) u32*)s, 16, 0, 0);
}

__device__ __forceinline__ f4 mfma(b8 a, b8 b, f4 c) {
    return __builtin_amdgcn_mfma_f32_16x16x32_bf16(a, b, c, 0, 0, 0);
}

__device__ __forceinline__ void split8(float4 a, float4 b, u16* dh, u16* dl) {
    float xs[8] = {a.x, a.y, a.z, a.w, b.x, b.y, b.z, b.w};
    union { u16 u[8]; b8 v; } H, L;
#pragma unroll
    for (int i = 0; i < 8; ++i) {
        u16 h = f2bf(xs[i]);
        H.u[i] = h;
        L.u[i] = f2bf(xs[i] - bf2f(h));
    }
    *(b8*)dh = H.v;
    *(b8*)dl = L.v;
}

// ---------------------------------------------------------------------------
// Merged prep:
//  [0,80)      split enc_w
//  [80,336)    split cb
//  [336,368)   cbnorm
//  [368,1618)  split wav
//  [1618,1666) dwf transpose: dwf[s][d] = dec_w[d][319-s], rows 320..383 zero
// ---------------------------------------------------------------------------
__global__ __launch_bounds__(256) void k_prep(const float* __restrict__ enc_w,
                                              u16* __restrict__ ewh, u16* __restrict__ ewl,
                                              const float* __restrict__ cb,
                                              u16* __restrict__ cbh, u16* __restrict__ cbl,
                                              const float* __restrict__ dw,
                                              u16* __restrict__ dwfh, u16* __restrict__ dwfl,
                                              float* __restrict__ cbn,
                                              const float* __restrict__ wav,
                                              u16* __restrict__ wavh, u16* __restrict__ wavl) {
    const int bid = blockIdx.x, tid = threadIdx.x;
    if (bid < 80) {
        int i = (bid * 256 + tid) * 8;
        float4 a = *(const float4*)&enc_w[i];
        float4 b = *(const float4*)&enc_w[i + 4];
        split8(a, b, &ewh[i], &ewl[i]);
    } else if (bid < 336) {
        int i = ((bid - 80) * 256 + tid) * 8;
        float4 a = *(const float4*)&cb[i];
        float4 b = *(const float4*)&cb[i + 4];
        split8(a, b, &cbh[i], &cbl[i]);
    } else if (bid < 368) {
        int c = (bid - 336) * 32 + (tid >> 3);
        int l = tid & 7;
        float s = 0.f;
        for (int j = l * 4; j < DD; j += 32) {
            float4 v = *(const float4*)&cb[c * DD + j];
            s += v.x * v.x + v.y * v.y + v.z * v.z + v.w * v.w;
        }
        s += __shfl_xor(s, 1);
        s += __shfl_xor(s, 2);
        s += __shfl_xor(s, 4);
        if (l == 0) cbn[c] = s;
    } else if (bid < 1618) {
        int i = ((bid - 368) * 256 + tid) * 8;  // FR*KSZ = 2,560,000
        float4 a = *(const float4*)&wav[i];
        float4 b = *(const float4*)&wav[i + 4];
        split8(a, b, &wavh[i], &wavl[i]);
    } else {
        int bid2 = bid - 1618;              // 48 blocks: 8 d x 6 s
        int d0 = (bid2 & 7) * 64;
        int sb = bid2 >> 3;
        int s0 = sb * 64;
        if (sb == 5) {                      // zero pad rows 320..383
            b8 z = {};
#pragma unroll
            for (int k = 0; k < 2; ++k) {
                int lin = tid * 2 + k;      // [0,512)
                int row = 320 + (lin >> 3);
                int col = (lin & 7) * 8;
                *(b8*)&dwfh[(size_t)row * DD + d0 + col] = z;
                *(b8*)&dwfl[(size_t)row * DD + d0 + col] = z;
            }
            return;
        }
        __shared__ float t64[64][68];
        const int u0 = 256 - s0;            // input col base (reversed range)
#pragma unroll
        for (int p = 0; p < 4; ++p) {
            int row = (tid >> 4) + 16 * p;
            int c4 = (tid & 15) * 4;
            float4 v = *(const float4*)&dw[(size_t)(d0 + row) * KSZ + u0 + c4];
            t64[row][c4] = v.x; t64[row][c4 + 1] = v.y;
            t64[row][c4 + 2] = v.z; t64[row][c4 + 3] = v.w;
        }
        __syncthreads();
        const int i = tid >> 2;             // s-local row
        const int jq = (tid & 3) * 16;      // d-local col base
        union { u16 u[8]; b8 v; } H0, L0, H1, L1;
#pragma unroll
        for (int j = 0; j < 8; ++j) {
            float m = t64[jq + j][63 - i];
            u16 h = f2bf(m);
            H0.u[j] = h; L0.u[j] = f2bf(m - bf2f(h));
            float m2 = t64[jq + 8 + j][63 - i];
            u16 h2 = f2bf(m2);
            H1.u[j] = h2; L1.u[j] = f2bf(m2 - bf2f(h2));
        }
        size_t o = (size_t)(s0 + i) * DD + d0 + jq;
        *(b8*)&dwfh[o] = H0.v; *(b8*)&dwfh[o + 8] = H1.v;
        *(b8*)&dwfl[o] = L0.v; *(b8*)&dwfl[o + 8] = L1.v;
    }
}

// Counted-vmcnt double-buffered pipeline (T3+T4), pure gld16 staging:
#define PIPELINE(NT, STRIDE)                                                  \
    stg(0, 0);                                                                \
    stg(1, STRIDE);                                                           \
    int cur = 0;                                                              \
    for (int t = 0; t < NT; ++t) {                                            \
        if (t < NT - 1) asm volatile("s_waitcnt vmcnt(8)" ::: "memory");      \
        else            asm volatile("s_waitcnt vmcnt(0)" ::: "memory");      \
        __builtin_amdgcn_s_barrier();                                         \
        asm volatile("" ::: "memory");                                        \
        compute(cur);                                                         \
        asm volatile("" ::: "memory");                                        \
        __builtin_amdgcn_s_barrier();                                         \
        if (t < NT - 2) stg(cur, (t + 2) * STRIDE);                           \
        cur ^= 1;                                                             \
    }

// ---------------------------------------------------------------------------
// Encoder MFMA GEMM: emb[f,d] = wav[f,:].enc_w[d,:] + eb[d]
// Grid 256 (1D, XCD-chunked): 64 f-panels x 4 d-panels.
// ---------------------------------------------------------------------------
__global__ __launch_bounds__(256, 2) void k_enc(const u16* __restrict__ Ahg,
                                                const u16* __restrict__ Alg,
                                                const u16* __restrict__ Bhg,
                                                const u16* __restrict__ Blg,
                                                const float* __restrict__ eb,
                                                u16* __restrict__ embh,
                                                u16* __restrict__ embl) {
    __shared__ __align__(16) u16 Ah[2][4096], Al[2][4096], Bh[2][4096], Bl[2][4096];
    const int tid = threadIdx.x;
    const int l = tid & 63, w = tid >> 6, wm = w >> 1, wn = w & 1;
    const int lane16 = l & 15, laneK = l >> 4;
    const int g = blockIdx.x;
    const int xcd = g & 7, slot = g >> 3;
    const int f0 = (xcd * 8 + (slot & 7)) * 128;
    const int d0 = (slot >> 3) * 128;

    const int p0 = w * 128 + l, p1 = p0 + 64;
    const int r0 = p0 >> 2, q0 = (p0 & 3) ^ ((r0 >> 1) & 3);
    const int r1 = p1 >> 2, q1 = (p1 & 3) ^ ((r1 >> 1) & 3);
    int fa0 = f0 + r0; if (fa0 > FR - 1) fa0 = FR - 1;
    int fa1 = f0 + r1; if (fa1 > FR - 1) fa1 = FR - 1;
    const u16* gA0h = Ahg + (size_t)fa0 * KSZ + q0 * 8;
    const u16* gA1h = Ahg + (size_t)fa1 * KSZ + q1 * 8;
    const u16* gA0l = Alg + (size_t)fa0 * KSZ + q0 * 8;
    const u16* gA1l = Alg + (size_t)fa1 * KSZ + q1 * 8;
    const u16* gB0h = Bhg + (size_t)(d0 + r0) * KSZ + q0 * 8;
    const u16* gB1h = Bhg + (size_t)(d0 + r1) * KSZ + q1 * 8;
    const u16* gB0l = Blg + (size_t)(d0 + r0) * KSZ + q0 * 8;
    const u16* gB1l = Blg + (size_t)(d0 + r1) * KSZ + q1 * 8;

    int offA[4], offB[4];
#pragma unroll
    for (int i = 0; i < 4; ++i) {
        int ra = wm * 64 + i * 16 + lane16;
        offA[i] = (ra * 4 + (laneK ^ ((ra >> 1) & 3))) * 8;
        int rb = wn * 64 + i * 16 + lane16;
        offB[i] = (rb * 4 + (laneK ^ ((rb >> 1) & 3))) * 8;
    }

    f4 zero = {0.f, 0.f, 0.f, 0.f};
    f4 acc[4][4];
#pragma unroll
    for (int i = 0; i < 4; ++i)
#pragma unroll
        for (int j = 0; j < 4; ++j) acc[i][j] = zero;

    auto stg = [&](int buf, int kt) {
        gld16(gA0h + kt, Ah[buf] + w * 1024);
        gld16(gA1h + kt, Ah[buf] + w * 1024 + 512);
        gld16(gA0l + kt, Al[buf] + w * 1024);
        gld16(gA1l + kt, Al[buf] + w * 1024 + 512);
        gld16(gB0h + kt, Bh[buf] + w * 1024);
        gld16(gB1h + kt, Bh[buf] + w * 1024 + 512);
        gld16(gB0l + kt, Bl[buf] + w * 1024);
        gld16(gB1l + kt, Bl[buf] + w * 1024 + 512);
    };
    auto compute = [&](int buf) {
        b8 ah[4], al[4], bh[4], bl[4];
#pragma unroll
        for (int i = 0; i < 4; ++i) {
            ah[i] = *(const b8*)(Ah[buf] + offA[i]);
            al[i] = *(const b8*)(Al[buf] + offA[i]);
            bh[i] = *(const b8*)(Bh[buf] + offB[i]);
            bl[i] = *(const b8*)(Bl[buf] + offB[i]);
        }
#pragma unroll
        for (int mi = 0; mi < 4; ++mi)
#pragma unroll
            for (int ni = 0; ni < 4; ++ni) {
                acc[mi][ni] = mfma(ah[mi], bh[ni], acc[mi][ni]);
                acc[mi][ni] = mfma(ah[mi], bl[ni], acc[mi][ni]);
                acc[mi][ni] = mfma(al[mi], bh[ni], acc[mi][ni]);
            }
    };

    PIPELINE(10, 32)

    float ebv[4];
#pragma unroll
    for (int ni = 0; ni < 4; ++ni) ebv[ni] = eb[d0 + wn * 64 + ni * 16 + lane16];
#pragma unroll
    for (int mi = 0; mi < 4; ++mi)
#pragma unroll
        for (int q = 0; q < 4; ++q) {
            int f = f0 + wm * 64 + mi * 16 + laneK * 4 + q;
#pragma unroll
            for (int ni = 0; ni < 4; ++ni) {
                int d = d0 + wn * 64 + ni * 16 + lane16;
                float v = acc[mi][ni][q] + ebv[ni];
                u16 h = f2bf(v);
                size_t o = (size_t)f * DD + d;
                embh[o] = h;
                embl[o] = f2bf(v - bf2f(h));
            }
        }
}

// ---------------------------------------------------------------------------
// time_avg, vectorized b8 loads
// ---------------------------------------------------------------------------
__global__ __launch_bounds__(256) void k_tavg(const u16* __restrict__ eh,
                                              const u16* __restrict__ el,
                                              float* __restrict__ tavg) {
    const int b = blockIdx.y, d0 = blockIdx.x * 64;
    const int dt = threadIdx.x & 7, tg = threadIdx.x >> 3;  // tg 0..31
    const int d = d0 + dt * 8;
    float s[8] = {};
    for (int t = tg; t < TT; t += 32) {
        size_t o = (size_t)(b * TT + t) * DD + d;
        b8 h = *(const b8*)(eh + o);
        b8 lo = *(const b8*)(el + o);
#pragma unroll
        for (int j = 0; j < 8; ++j) s[j] += bf2f((u16)h[j]) + bf2f((u16)lo[j]);
    }
#pragma unroll
    for (int m = 8; m <= 32; m <<= 1)
#pragma unroll
        for (int j = 0; j < 8; ++j) s[j] += __shfl_xor(s[j], m);
    __shared__ float red[4][64];
    const int w = threadIdx.x >> 6;
    if ((threadIdx.x & 63) < 8)
#pragma unroll
        for (int j = 0; j < 8; ++j) red[w][dt * 8 + j] = s[j];
    __syncthreads();
    if (threadIdx.x < 64)
        tavg[b * DD + d0 + threadIdx.x] =
            (red[0][threadIdx.x] + red[1][threadIdx.x] +
             red[2][threadIdx.x] + red[3][threadIdx.x]) * (1.0f / TT);
}

// ---------------------------------------------------------------------------
// cond[b,i] = tavg[b,:].lin_w[i,:] + lin_b[i]
// ---------------------------------------------------------------------------
__global__ __launch_bounds__(256) void k_cond(const float* __restrict__ tavg,
                                              const float* __restrict__ lw,
                                              const float* __restrict__ lb,
                                              float* __restrict__ cond) {
    __shared__ float stv[NB * DD];
    for (int i = threadIdx.x * 4; i < NB * DD; i += 1024)
        *(float4*)&stv[i] = *(const float4*)&tavg[i];
    __syncthreads();
    const int w = threadIdx.x >> 6, lane = threadIdx.x & 63;
    const int row = blockIdx.x * 4 + w;
    float wv[8];
#pragma unroll
    for (int j = 0; j < 8; ++j) wv[j] = lw[(size_t)row * DD + lane + 64 * j];
    float r[NB];
#pragma unroll
    for (int b = 0; b < NB; ++b) {
        float s = 0.f;
#pragma unroll
        for (int j = 0; j < 8; ++j) s += wv[j] * stv[b * DD + lane + 64 * j];
        r[b] = s;
    }
#pragma unroll
    for (int m = 32; m >= 1; m >>= 1)
#pragma unroll
        for (int b = 0; b < NB; ++b) r[b] += __shfl_xor(r[b], m);
    if (lane < NB) cond[lane * DD + row] = r[lane] + lb[row];
}

__global__ __launch_bounds__(256) void k_film(const float* __restrict__ cond,
                                              const float* __restrict__ fw,
                                              const float* __restrict__ fb,
                                              float* __restrict__ gbv) {
    __shared__ float sc[NB * DD];
    for (int i = threadIdx.x * 4; i < NB * DD; i += 1024)
        *(float4*)&sc[i] = *(const float4*)&cond[i];
    __syncthreads();
    const int w = threadIdx.x >> 6, lane = threadIdx.x & 63;
    const int row = blockIdx.x * 4 + w;
    float wv[8];
#pragma unroll
    for (int j = 0; j < 8; ++j) wv[j] = fw[(size_t)row * DD + lane + 64 * j];
    float r[NB];
#pragma unroll
    for (int b = 0; b < NB; ++b) {
        float s = 0.f;
#pragma unroll
        for (int j = 0; j < 8; ++j) s += wv[j] * sc[b * DD + lane + 64 * j];
        r[b] = s;
    }
#pragma unroll
    for (int m = 32; m >= 1; m >>= 1)
#pragma unroll
        for (int b = 0; b < NB; ++b) r[b] += __shfl_xor(r[b], m);
    if (lane < NB) gbv[lane * 2 * DD + row] = r[lane] + fb[row];
}

// ---------------------------------------------------------------------------
// VQ dist MFMA + fused per-block argmin. Grid 512 (1D, XCD-chunked).
// ---------------------------------------------------------------------------
__global__ __launch_bounds__(256, 2) void k_dist(const u16* __restrict__ Ahg,
                                                 const u16* __restrict__ Alg,
                                                 const u16* __restrict__ Bhg,
                                                 const u16* __restrict__ Blg,
                                                 const float* __restrict__ cbn,
                                                 float* __restrict__ pmin,
                                                 int* __restrict__ pidx) {
    __shared__ __align__(16) u16 Ah[2][4096], Al[2][4096], Bh[2][4096], Bl[2][4096];
    __shared__ float s_best[128][2];
    __shared__ int s_bidx[128][2];
    const int tid = threadIdx.x;
    const int l = tid & 63, w = tid >> 6, wm = w >> 1, wn = w & 1;
    const int lane16 = l & 15, laneK = l >> 4;
    const int g = blockIdx.x;
    const int xcd = g & 7, slot = g >> 3;
    const int f0 = (xcd * 8 + (slot & 7)) * 128;
    const int cy = slot >> 3;
    const int c0 = cy * 128;

    const int p0 = w * 128 + l, p1 = p0 + 64;
    const int r0 = p0 >> 2, q0 = (p0 & 3) ^ ((r0 >> 1) & 3);
    const int r1 = p1 >> 2, q1 = (p1 & 3) ^ ((r1 >> 1) & 3);
    const u16* gA0h = Ahg + (size_t)(f0 + r0) * DD + q0 * 8;
    const u16* gA1h = Ahg + (size_t)(f0 + r1) * DD + q1 * 8;
    const u16* gA0l = Alg + (size_t)(f0 + r0) * DD + q0 * 8;
    const u16* gA1l = Alg + (size_t)(f0 + r1) * DD + q1 * 8;
    const u16* gB0h = Bhg + (size_t)(c0 + r0) * DD + q0 * 8;
    const u16* gB1h = Bhg + (size_t)(c0 + r1) * DD + q1 * 8;
    const u16* gB0l = Blg + (size_t)(c0 + r0) * DD + q0 * 8;
    const u16* gB1l = Blg + (size_t)(c0 + r1) * DD + q1 * 8;

    int offA[4], offB[4];
#pragma unroll
    for (int i = 0; i < 4; ++i) {
        int ra = wm * 64 + i * 16 + lane16;
        offA[i] = (ra * 4 + (laneK ^ ((ra >> 1) & 3))) * 8;
        int rb = wn * 64 + i * 16 + lane16;
        offB[i] = (rb * 4 + (laneK ^ ((rb >> 1) & 3))) * 8;
    }

    f4 zero = {0.f, 0.f, 0.f, 0.f};
    f4 acc[4][4];
#pragma unroll
    for (int i = 0; i < 4; ++i)
#pragma unroll
        for (int j = 0; j < 4; ++j) acc[i][j] = zero;

    auto stg = [&](int buf, int kt) {
        gld16(gA0h + kt, Ah[buf] + w * 1024);
        gld16(gA1h + kt, Ah[buf] + w * 1024 + 512);
        gld16(gA0l + kt, Al[buf] + w * 1024);
        gld16(gA1l + kt, Al[buf] + w * 1024 + 512);
        gld16(gB0h + kt, Bh[buf] + w * 1024);
        gld16(gB1h + kt, Bh[buf] + w * 1024 + 512);
        gld16(gB0l + kt, Bl[buf] + w * 1024);
        gld16(gB1l + kt, Bl[buf] + w * 1024 + 512);
    };
    auto compute = [&](int buf) {
        b8 ah[4], al[4], bh[4], bl[4];
#pragma unroll
        for (int i = 0; i < 4; ++i) {
            ah[i] = *(const b8*)(Ah[buf] + offA[i]);
            al[i] = *(const b8*)(Al[buf] + offA[i]);
            bh[i] = *(const b8*)(Bh[buf] + offB[i]);
            bl[i] = *(const b8*)(Bl[buf] + offB[i]);
        }
#pragma unroll
        for (int mi = 0; mi < 4; ++mi)
#pragma unroll
            for (int ni = 0; ni < 4; ++ni) {
                acc[mi][ni] = mfma(ah[mi], bh[ni], acc[mi][ni]);
                acc[mi][ni] = mfma(ah[mi], bl[ni], acc[mi][ni]);
                acc[mi][ni] = mfma(al[mi], bh[ni], acc[mi][ni]);
            }
    };

    PIPELINE(16, 32)

    float cbv[4];
    int cidx[4];
#pragma unroll
    for (int ni = 0; ni < 4; ++ni) {
        cidx[ni] = c0 + wn * 64 + ni * 16 + lane16;
        cbv[ni] = cbn[cidx[ni]];
    }
#pragma unroll
    for (int mi = 0; mi < 4; ++mi)
#pragma unroll
        for (int q = 0; q < 4; ++q) {
            float best = 3.4e38f;
            int bi = 0x7fffffff;
#pragma unroll
            for (int ni = 0; ni < 4; ++ni) {
                float s = cbv[ni] - 2.0f * acc[mi][ni][q];
                if (s < best || (s == best && cidx[ni] < bi)) { best = s; bi = cidx[ni]; }
            }
#pragma unroll
            for (int m = 8; m >= 1; m >>= 1) {
                float os = __shfl_xor(best, m);
                int oi = __shfl_xor(bi, m);
                if (os < best || (os == best && oi < bi)) { best = os; bi = oi; }
            }
            if (lane16 == 0) {
                int rl = wm * 64 + mi * 16 + laneK * 4 + q;
                s_best[rl][wn] = best;
                s_bidx[rl][wn] = bi;
            }
        }
    __syncthreads();
    if (tid < 128) {
        float b0 = s_best[tid][0], b1 = s_best[tid][1];
        int i0 = s_bidx[tid][0], i1 = s_bidx[tid][1];
        bool t1 = (b1 < b0) || (b1 == b0 && i1 < i0);
        int f = f0 + tid;
        if (f < FR) {
            pmin[f * 8 + cy] = t1 ? b1 : b0;
            pidx[f * 8 + cy] = t1 ? i1 : i0;
        }
    }
}

// ---------------------------------------------------------------------------
// Decoder MFMA GEMM with FUSED combine + gather + FiLM + split in A-staging.
// out[f*320+s] = (gamma*cb[code[f]]+beta)[f,:].dwf[s,:] + db
// Grid (3, 63): x = s-panel (fastest) so consecutive blocks share A work.
// A: reg-staged ds_write (XOR swizzle); B: gld16. lgkmcnt(0) before the
// pre-compute barrier makes the ds_writes visible.
// ---------------------------------------------------------------------------
__global__ __launch_bounds__(256, 2) void k_dec(const float* __restrict__ pmin,
                                                const int* __restrict__ pidx,
                                                const float* __restrict__ cb,
                                                const float* __restrict__ gbv,
                                                const u16* __restrict__ Bhg,
                                                const u16* __restrict__ Blg,
                                                const float* __restrict__ db,
                                                float* __restrict__ out) {
    __shared__ __align__(16) u16 Ah[2][4096], Al[2][4096], Bh[2][4096], Bl[2][4096];
    __shared__ int codes_lds[128];
    __shared__ int b_lds[128];
    const int tid = threadIdx.x;
    const int l = tid & 63, w = tid >> 6, wm = w >> 1, wn = w & 1;
    const int lane16 = l & 15, laneK = l >> 4;
    const int f0 = blockIdx.y * 128, s0 = blockIdx.x * 128;

    // combine partial argmins -> codes for this f-panel
    if (tid < 128) {
        int f = f0 + tid;
        int fc = (f < FR) ? f : FR - 1;
        float best = pmin[fc * 8];
        int bi = pidx[fc * 8];
#pragma unroll
        for (int y = 1; y < 8; ++y) {
            float s = pmin[fc * 8 + y];
            if (s < best) { best = s; bi = pidx[fc * 8 + y]; }
        }
        codes_lds[tid] = bi;
        b_lds[tid] = fc / TT;
    }
    __syncthreads();

    // B staging (gld16)
    const int p0 = w * 128 + l, p1 = p0 + 64;
    const int r0 = p0 >> 2, q0 = (p0 & 3) ^ ((r0 >> 1) & 3);
    const int r1 = p1 >> 2, q1 = (p1 & 3) ^ ((r1 >> 1) & 3);
    const u16* gB0h = Bhg + (size_t)(s0 + r0) * DD + q0 * 8;
    const u16* gB1h = Bhg + (size_t)(s0 + r1) * DD + q1 * 8;
    const u16* gB0l = Blg + (size_t)(s0 + r0) * DD + q0 * 8;
    const u16* gB1l = Blg + (size_t)(s0 + r1) * DD + q1 * 8;

    // A staging (reg->ds_write): rows ra0 (0..63), ra1 (64..127)
    const int pa0 = tid, pa1 = tid + 256;
    const int ra0 = pa0 >> 2, qa0 = (pa0 & 3) ^ ((ra0 >> 1) & 3);
    const int ra1 = pa1 >> 2, qa1 = (pa1 & 3) ^ ((ra1 >> 1) & 3);
    const float* cp0 = cb + (size_t)codes_lds[ra0] * DD + qa0 * 8;
    const float* cp1 = cb + (size_t)codes_lds[ra1] * DD + qa1 * 8;
    const float* gp0 = gbv + b_lds[ra0] * 2 * DD + qa0 * 8;
    const float* gp1 = gbv + b_lds[ra1] * 2 * DD + qa1 * 8;

    int offA[4], offB[4];
#pragma unroll
    for (int i = 0; i < 4; ++i) {
        int ra = wm * 64 + i * 16 + lane16;
        offA[i] = (ra * 4 + (laneK ^ ((ra >> 1) & 3))) * 8;
        int rb = wn * 64 + i * 16 + lane16;
        offB[i] = (rb * 4 + (laneK ^ ((rb >> 1) & 3))) * 8;
    }

    f4 zero = {0.f, 0.f, 0.f, 0.f};
    f4 acc[4][4];
#pragma unroll
    for (int i = 0; i < 4; ++i)
#pragma unroll
        for (int j = 0; j < 4; ++j) acc[i][j] = zero;

    auto stgB = [&](int buf, int kt) {
        gld16(gB0h + kt, Bh[buf] + w * 1024);
        gld16(gB1h + kt, Bh[buf] + w * 1024 + 512);
        gld16(gB0l + kt, Bl[buf] + w * 1024);
        gld16(gB1l + kt, Bl[buf] + w * 1024 + 512);
    };
    auto stageA = [&](int buf, int kt) {
        float4 c00 = *(const float4*)(cp0 + kt);
        float4 c01 = *(const float4*)(cp0 + kt + 4);
        float4 g00 = *(const float4*)(gp0 + kt);
        float4 g01 = *(const float4*)(gp0 + kt + 4);
        float4 e00 = *(const float4*)(gp0 + DD + kt);
        float4 e01 = *(const float4*)(gp0 + DD + kt + 4);
        float4 c10 = *(const float4*)(cp1 + kt);
        float4 c11 = *(const float4*)(cp1 + kt + 4);
        float4 g10 = *(const float4*)(gp1 + kt);
        float4 g11 = *(const float4*)(gp1 + kt + 4);
        float4 e10 = *(const float4*)(gp1 + DD + kt);
        float4 e11 = *(const float4*)(gp1 + DD + kt + 4);
        float4 m00, m01, m10, m11;
        m00.x = g00.x * c00.x + e00.x; m00.y = g00.y * c00.y + e00.y;
        m00.z = g00.z * c00.z + e00.z; m00.w = g00.w * c00.w + e00.w;
        m01.x = g01.x * c01.x + e01.x; m01.y = g01.y * c01.y + e01.y;
        m01.z = g01.z * c01.z + e01.z; m01.w = g01.w * c01.w + e01.w;
        m10.x = g10.x * c10.x + e10.x; m10.y = g10.y * c10.y + e10.y;
        m10.z = g10.z * c10.z + e10.z; m10.w = g10.w * c10.w + e10.w;
        m11.x = g11.x * c11.x + e11.x; m11.y = g11.y * c11.y + e11.y;
        m11.z = g11.z * c11.z + e11.z; m11.w = g11.w * c11.w + e11.w;
        split8(m00, m01, Ah[buf] + pa0 * 8, Al[buf] + pa0 * 8);
        split8(m10, m11, Ah[buf] + pa1 * 8, Al[buf] + pa1 * 8);
    };
    auto compute = [&](int buf) {
        b8 ah[4], al[4], bh[4], bl[4];
#pragma unroll
        for (int i = 0; i < 4; ++i) {
            ah[i] = *(const b8*)(Ah[buf] + offA[i]);
            al[i] = *(const b8*)(Al[buf] + offA[i]);
            bh[i] = *(const b8*)(Bh[buf] + offB[i]);
            bl[i] = *(const b8*)(Bl[buf] + offB[i]);
        }
#pragma unroll
        for (int mi = 0; mi < 4; ++mi)
#pragma unroll
            for (int ni = 0; ni < 4; ++ni) {
                acc[mi][ni] = mfma(ah[mi], bh[ni], acc[mi][ni]);
                acc[mi][ni] = mfma(ah[mi], bl[ni], acc[mi][ni]);
                acc[mi][ni] = mfma(al[mi], bh[ni], acc[mi][ni]);
            }
    };

    stgB(0, 0); stageA(0, 0);
    stgB(1, 32); stageA(1, 32);
    int cur = 0;
    for (int t = 0; t < 16; ++t) {
        asm volatile("s_waitcnt vmcnt(0) lgkmcnt(0)" ::: "memory");
        __builtin_amdgcn_s_barrier();
        asm volatile("" ::: "memory");
        compute(cur);
        asm volatile("" ::: "memory");
        __builtin_amdgcn_s_barrier();
        if (t < 14) { stgB(cur, (t + 2) * 32); stageA(cur, (t + 2) * 32); }
        cur ^= 1;
    }

    const float d0v = db[0];
#pragma unroll
    for (int mi = 0; mi < 4; ++mi)
#pragma unroll
        for (int q = 0; q < 4; ++q) {
            int f = f0 + wm * 64 + mi * 16 + laneK * 4 + q;
            if (f < FR) {
#pragma unroll
                for (int ni = 0; ni < 4; ++ni) {
                    int s = s0 + wn * 64 + ni * 16 + lane16;
                    if (s < KSZ) out[(size_t)f * KSZ + s] = acc[mi][ni][q] + d0v;
                }
            }
        }
}

// ---------------------------------------------------------------------------
extern "C" void kernel_launch(void* const* d_in, const int* in_sizes, int n_in,
                              void* d_out, int out_size, void* d_ws, size_t ws_size,
                              hipStream_t stream) {
    const float* wav    = (const float*)d_in[0];
    const float* enc_w  = (const float*)d_in[1];
    const float* enc_b  = (const float*)d_in[2];
    const float* cb     = (const float*)d_in[3];
    const float* lin_w  = (const float*)d_in[4];
    const float* lin_b  = (const float*)d_in[5];
    const float* film_w = (const float*)d_in[6];
    const float* film_b = (const float*)d_in[7];
    const float* dec_w  = (const float*)d_in[8];
    const float* dec_b  = (const float*)d_in[9];
    float* out = (float*)d_out;

    char* p = (char*)d_ws;
    u16* embh = (u16*)p;                 p += (size_t)FRP * DD * 2;
    u16* embl = (u16*)p;                 p += (size_t)FRP * DD * 2;
    u16* wavh = (u16*)p;                 p += (size_t)FR * KSZ * 2;
    u16* wavl = (u16*)p;                 p += (size_t)FR * KSZ * 2;
    u16* ewh  = (u16*)p;                 p += (size_t)DD * KSZ * 2;
    u16* ewl  = (u16*)p;                 p += (size_t)DD * KSZ * 2;
    u16* cbh  = (u16*)p;                 p += (size_t)CK * DD * 2;
    u16* cbl  = (u16*)p;                 p += (size_t)CK * DD * 2;
    u16* dwfh = (u16*)p;                 p += (size_t)384 * DD * 2;
    u16* dwfl = (u16*)p;                 p += (size_t)384 * DD * 2;
    float* cbn  = (float*)p;             p += CK * 4;
    float* tavg = (float*)p;             p += NB * DD * 4;
    float* cond = (float*)p;             p += NB * DD * 4;
    float* gbv  = (float*)p;             p += NB * 2 * DD * 4;
    float* pmin = (float*)p;             p += FR * 8 * 4;
    int*   pidx = (int*)p;               p += FR * 8 * 4;

    k_prep<<<dim3(1666), 256, 0, stream>>>(enc_w, ewh, ewl, cb, cbh, cbl,
                                           dec_w, dwfh, dwfl, cbn, wav, wavh, wavl);
    k_enc<<<dim3(256), 256, 0, stream>>>(wavh, wavl, ewh, ewl, enc_b, embh, embl);
    k_tavg<<<dim3(8, NB), 256, 0, stream>>>(embh, embl, tavg);
    k_cond<<<dim3(128), 256, 0, stream>>>(tavg, lin_w, lin_b, cond);
    k_film<<<dim3(256), 256, 0, stream>>>(cond, film_w, film_b, gbv);
    k_dist<<<dim3(512), 256, 0, stream>>>(embh, embl, cbh, cbl, cbn, pmin, pidx);
    k_dec<<<dim3(3, 63), 256, 0, stream>>>(pmin, pidx, cb, gbv, dwfh, dwfl, dec_b, out);
}

// Round 7
// 172.909 us; speedup vs baseline: 2.7975x; 1.0422x over previous
//
#include <hip/hip_runtime.h>

#define FR   8000
#define FRP  8192    // padded to 64*128 for XCD-chunked dist mapping
#define DD   512
#define CK   1024
#define KSZ  320
#define TT   500
#define NB   16

typedef unsigned int u32;
typedef unsigned short u16;
typedef __attribute__((ext_vector_type(8))) short b8;   // 8 x bf16 bits
typedef __attribute__((ext_vector_type(4))) float f4;

__device__ __forceinline__ float bf2f(u16 h) {
    u32 u = ((u32)h) << 16;
    return __builtin_bit_cast(float, u);
}
__device__ __forceinline__ u16 f2bf(float f) {  // RNE
    u32 u = __builtin_bit_cast(u32, f);
    u32 r = u + 0x7FFFu + ((u >> 16) & 1u);
    return (u16)(r >> 16);
}

__device__ __forceinline__ void gld16(const u16* g, u16* s) {
    __builtin_amdgcn_global_load_lds(
        (const __attribute__((address_space(1))) u32*)g,
        (__attribute__((address_space(3))) u32*)s, 16, 0, 0);
}

__device__ __forceinline__ f4 mfma(b8 a, b8 b, f4 c) {
    return __builtin_amdgcn_mfma_f32_16x16x32_bf16(a, b, c, 0, 0, 0);
}

__device__ __forceinline__ void split8(float4 a, float4 b, u16* dh, u16* dl) {
    float xs[8] = {a.x, a.y, a.z, a.w, b.x, b.y, b.z, b.w};
    union { u16 u[8]; b8 v; } H, L;
#pragma unroll
    for (int i = 0; i < 8; ++i) {
        u16 h = f2bf(xs[i]);
        H.u[i] = h;
        L.u[i] = f2bf(xs[i] - bf2f(h));
    }
    *(b8*)dh = H.v;
    *(b8*)dl = L.v;
}

// ---------------------------------------------------------------------------
// Merged prep:
//  [0,80)      split enc_w
//  [80,336)    split cb
//  [336,368)   cbnorm
//  [368,1618)  split wav
//  [1618,1666) dwf transpose: dwf[s][d] = dec_w[d][319-s], rows 320..383 zero
//  [1666]      zero tavg accumulator (for k_enc atomics)
// ---------------------------------------------------------------------------
__global__ __launch_bounds__(256) void k_prep(const float* __restrict__ enc_w,
                                              u16* __restrict__ ewh, u16* __restrict__ ewl,
                                              const float* __restrict__ cb,
                                              u16* __restrict__ cbh, u16* __restrict__ cbl,
                                              const float* __restrict__ dw,
                                              u16* __restrict__ dwfh, u16* __restrict__ dwfl,
                                              float* __restrict__ cbn,
                                              const float* __restrict__ wav,
                                              u16* __restrict__ wavh, u16* __restrict__ wavl,
                                              float* __restrict__ tsum) {
    const int bid = blockIdx.x, tid = threadIdx.x;
    if (bid < 80) {
        int i = (bid * 256 + tid) * 8;
        float4 a = *(const float4*)&enc_w[i];
        float4 b = *(const float4*)&enc_w[i + 4];
        split8(a, b, &ewh[i], &ewl[i]);
    } else if (bid < 336) {
        int i = ((bid - 80) * 256 + tid) * 8;
        float4 a = *(const float4*)&cb[i];
        float4 b = *(const float4*)&cb[i + 4];
        split8(a, b, &cbh[i], &cbl[i]);
    } else if (bid < 368) {
        int c = (bid - 336) * 32 + (tid >> 3);
        int l = tid & 7;
        float s = 0.f;
        for (int j = l * 4; j < DD; j += 32) {
            float4 v = *(const float4*)&cb[c * DD + j];
            s += v.x * v.x + v.y * v.y + v.z * v.z + v.w * v.w;
        }
        s += __shfl_xor(s, 1);
        s += __shfl_xor(s, 2);
        s += __shfl_xor(s, 4);
        if (l == 0) cbn[c] = s;
    } else if (bid < 1618) {
        int i = ((bid - 368) * 256 + tid) * 8;  // FR*KSZ = 2,560,000
        float4 a = *(const float4*)&wav[i];
        float4 b = *(const float4*)&wav[i + 4];
        split8(a, b, &wavh[i], &wavl[i]);
    } else if (bid < 1666) {
        int bid2 = bid - 1618;              // 48 blocks: 8 d x 6 s
        int d0 = (bid2 & 7) * 64;
        int sb = bid2 >> 3;
        int s0 = sb * 64;
        if (sb == 5) {                      // zero pad rows 320..383
            b8 z = {};
#pragma unroll
            for (int k = 0; k < 2; ++k) {
                int lin = tid * 2 + k;      // [0,512)
                int row = 320 + (lin >> 3);
                int col = (lin & 7) * 8;
                *(b8*)&dwfh[(size_t)row * DD + d0 + col] = z;
                *(b8*)&dwfl[(size_t)row * DD + d0 + col] = z;
            }
            return;
        }
        __shared__ float t64[64][68];
        const int u0 = 256 - s0;            // input col base (reversed range)
#pragma unroll
        for (int p = 0; p < 4; ++p) {
            int row = (tid >> 4) + 16 * p;
            int c4 = (tid & 15) * 4;
            float4 v = *(const float4*)&dw[(size_t)(d0 + row) * KSZ + u0 + c4];
            t64[row][c4] = v.x; t64[row][c4 + 1] = v.y;
            t64[row][c4 + 2] = v.z; t64[row][c4 + 3] = v.w;
        }
        __syncthreads();
        const int i = tid >> 2;             // s-local row
        const int jq = (tid & 3) * 16;      // d-local col base
        union { u16 u[8]; b8 v; } H0, L0, H1, L1;
#pragma unroll
        for (int j = 0; j < 8; ++j) {
            float m = t64[jq + j][63 - i];
            u16 h = f2bf(m);
            H0.u[j] = h; L0.u[j] = f2bf(m - bf2f(h));
            float m2 = t64[jq + 8 + j][63 - i];
            u16 h2 = f2bf(m2);
            H1.u[j] = h2; L1.u[j] = f2bf(m2 - bf2f(h2));
        }
        size_t o = (size_t)(s0 + i) * DD + d0 + jq;
        *(b8*)&dwfh[o] = H0.v; *(b8*)&dwfh[o + 8] = H1.v;
        *(b8*)&dwfl[o] = L0.v; *(b8*)&dwfl[o + 8] = L1.v;
    } else {
        // zero tavg accumulator: NB*DD = 8192 floats
        float4 z = {0.f, 0.f, 0.f, 0.f};
#pragma unroll
        for (int k = 0; k < 8; ++k)
            *(float4*)&tsum[(tid * 8 + k) * 4] = z;
    }
}

// Counted-vmcnt double-buffered pipeline (T3+T4), pure gld16 staging:
#define PIPELINE(NT, STRIDE)                                                  \
    stg(0, 0);                                                                \
    stg(1, STRIDE);                                                           \
    int cur = 0;                                                              \
    for (int t = 0; t < NT; ++t) {                                            \
        if (t < NT - 1) asm volatile("s_waitcnt vmcnt(8)" ::: "memory");      \
        else            asm volatile("s_waitcnt vmcnt(0)" ::: "memory");      \
        __builtin_amdgcn_s_barrier();                                         \
        asm volatile("" ::: "memory");                                        \
        compute(cur);                                                         \
        asm volatile("" ::: "memory");                                        \
        __builtin_amdgcn_s_barrier();                                         \
        if (t < NT - 2) stg(cur, (t + 2) * STRIDE);                           \
        cur ^= 1;                                                             \
    }

// ---------------------------------------------------------------------------
// Encoder MFMA GEMM + FUSED time-avg partials:
// emb[f,d] = wav[f,:].enc_w[d,:] + eb[d];  tsum[b,d] += sum_f emb[f,d]
// Grid 256 (1D, XCD-chunked): 64 f-panels x 4 d-panels.
// ---------------------------------------------------------------------------
__global__ __launch_bounds__(256, 2) void k_enc(const u16* __restrict__ Ahg,
                                                const u16* __restrict__ Alg,
                                                const u16* __restrict__ Bhg,
                                                const u16* __restrict__ Blg,
                                                const float* __restrict__ eb,
                                                u16* __restrict__ embh,
                                                u16* __restrict__ embl,
                                                float* __restrict__ tsum) {
    __shared__ __align__(16) u16 Ah[2][4096], Al[2][4096], Bh[2][4096], Bl[2][4096];
    __shared__ float tred[2][128][2];
    const int tid = threadIdx.x;
    const int l = tid & 63, w = tid >> 6, wm = w >> 1, wn = w & 1;
    const int lane16 = l & 15, laneK = l >> 4;
    const int g = blockIdx.x;
    const int xcd = g & 7, slot = g >> 3;
    const int f0 = (xcd * 8 + (slot & 7)) * 128;
    const int d0 = (slot >> 3) * 128;

    const int p0 = w * 128 + l, p1 = p0 + 64;
    const int r0 = p0 >> 2, q0 = (p0 & 3) ^ ((r0 >> 1) & 3);
    const int r1 = p1 >> 2, q1 = (p1 & 3) ^ ((r1 >> 1) & 3);
    int fa0 = f0 + r0; if (fa0 > FR - 1) fa0 = FR - 1;
    int fa1 = f0 + r1; if (fa1 > FR - 1) fa1 = FR - 1;
    const u16* gA0h = Ahg + (size_t)fa0 * KSZ + q0 * 8;
    const u16* gA1h = Ahg + (size_t)fa1 * KSZ + q1 * 8;
    const u16* gA0l = Alg + (size_t)fa0 * KSZ + q0 * 8;
    const u16* gA1l = Alg + (size_t)fa1 * KSZ + q1 * 8;
    const u16* gB0h = Bhg + (size_t)(d0 + r0) * KSZ + q0 * 8;
    const u16* gB1h = Bhg + (size_t)(d0 + r1) * KSZ + q1 * 8;
    const u16* gB0l = Blg + (size_t)(d0 + r0) * KSZ + q0 * 8;
    const u16* gB1l = Blg + (size_t)(d0 + r1) * KSZ + q1 * 8;

    int offA[4], offB[4];
#pragma unroll
    for (int i = 0; i < 4; ++i) {
        int ra = wm * 64 + i * 16 + lane16;
        offA[i] = (ra * 4 + (laneK ^ ((ra >> 1) & 3))) * 8;
        int rb = wn * 64 + i * 16 + lane16;
        offB[i] = (rb * 4 + (laneK ^ ((rb >> 1) & 3))) * 8;
    }

    f4 zero = {0.f, 0.f, 0.f, 0.f};
    f4 acc[4][4];
#pragma unroll
    for (int i = 0; i < 4; ++i)
#pragma unroll
        for (int j = 0; j < 4; ++j) acc[i][j] = zero;

    auto stg = [&](int buf, int kt) {
        gld16(gA0h + kt, Ah[buf] + w * 1024);
        gld16(gA1h + kt, Ah[buf] + w * 1024 + 512);
        gld16(gA0l + kt, Al[buf] + w * 1024);
        gld16(gA1l + kt, Al[buf] + w * 1024 + 512);
        gld16(gB0h + kt, Bh[buf] + w * 1024);
        gld16(gB1h + kt, Bh[buf] + w * 1024 + 512);
        gld16(gB0l + kt, Bl[buf] + w * 1024);
        gld16(gB1l + kt, Bl[buf] + w * 1024 + 512);
    };
    auto compute = [&](int buf) {
        b8 ah[4], al[4], bh[4], bl[4];
#pragma unroll
        for (int i = 0; i < 4; ++i) {
            ah[i] = *(const b8*)(Ah[buf] + offA[i]);
            al[i] = *(const b8*)(Al[buf] + offA[i]);
            bh[i] = *(const b8*)(Bh[buf] + offB[i]);
            bl[i] = *(const b8*)(Bl[buf] + offB[i]);
        }
#pragma unroll
        for (int mi = 0; mi < 4; ++mi)
#pragma unroll
            for (int ni = 0; ni < 4; ++ni) {
                acc[mi][ni] = mfma(ah[mi], bh[ni], acc[mi][ni]);
                acc[mi][ni] = mfma(ah[mi], bl[ni], acc[mi][ni]);
                acc[mi][ni] = mfma(al[mi], bh[ni], acc[mi][ni]);
            }
    };

    PIPELINE(10, 32)

    float ebv[4];
#pragma unroll
    for (int ni = 0; ni < 4; ++ni) ebv[ni] = eb[d0 + wn * 64 + ni * 16 + lane16];

    const int bA = f0 / TT;
    const int fB = min((bA + 1) * TT, f0 + 128);  // batch boundary (global f)
    float sumA[4] = {}, sumB[4] = {};
#pragma unroll
    for (int mi = 0; mi < 4; ++mi)
#pragma unroll
        for (int q = 0; q < 4; ++q) {
            int f = f0 + wm * 64 + mi * 16 + laneK * 4 + q;
            bool live = f < FR;
            bool sideA = f < fB;
#pragma unroll
            for (int ni = 0; ni < 4; ++ni) {
                int d = d0 + wn * 64 + ni * 16 + lane16;
                float v = acc[mi][ni][q] + ebv[ni];
                u16 h = f2bf(v);
                size_t o = (size_t)f * DD + d;
                embh[o] = h;
                embl[o] = f2bf(v - bf2f(h));
                if (live) { if (sideA) sumA[ni] += v; else sumB[ni] += v; }
            }
        }
    // reduce over laneK (lane bits 4..5)
#pragma unroll
    for (int m = 16; m <= 32; m <<= 1)
#pragma unroll
        for (int ni = 0; ni < 4; ++ni) {
            sumA[ni] += __shfl_xor(sumA[ni], m);
            sumB[ni] += __shfl_xor(sumB[ni], m);
        }
    if (laneK == 0)
#pragma unroll
        for (int ni = 0; ni < 4; ++ni) {
            tred[wm][wn * 64 + ni * 16 + lane16][0] = sumA[ni];
            tred[wm][wn * 64 + ni * 16 + lane16][1] = sumB[ni];
        }
    __syncthreads();
    if (tid < 128 && bA < NB) {
        float a = tred[0][tid][0] + tred[1][tid][0];
        int d = d0 + tid;
        atomicAdd(&tsum[bA * DD + d], a);
        if (fB < f0 + 128 && bA + 1 < NB) {
            float b = tred[0][tid][1] + tred[1][tid][1];
            atomicAdd(&tsum[(bA + 1) * DD + d], b);
        }
    }
}

// ---------------------------------------------------------------------------
// cond[b,i] = (tsum[b,:]/TT).lin_w[i,:] + lin_b[i]
// ---------------------------------------------------------------------------
__global__ __launch_bounds__(256) void k_cond(const float* __restrict__ tsum,
                                              const float* __restrict__ lw,
                                              const float* __restrict__ lb,
                                              float* __restrict__ cond) {
    __shared__ float stv[NB * DD];
    const float inv = 1.0f / TT;
    for (int i = threadIdx.x * 4; i < NB * DD; i += 1024) {
        float4 v = *(const float4*)&tsum[i];
        v.x *= inv; v.y *= inv; v.z *= inv; v.w *= inv;
        *(float4*)&stv[i] = v;
    }
    __syncthreads();
    const int w = threadIdx.x >> 6, lane = threadIdx.x & 63;
    const int row = blockIdx.x * 4 + w;
    float wv[8];
#pragma unroll
    for (int j = 0; j < 8; ++j) wv[j] = lw[(size_t)row * DD + lane + 64 * j];
    float r[NB];
#pragma unroll
    for (int b = 0; b < NB; ++b) {
        float s = 0.f;
#pragma unroll
        for (int j = 0; j < 8; ++j) s += wv[j] * stv[b * DD + lane + 64 * j];
        r[b] = s;
    }
#pragma unroll
    for (int m = 32; m >= 1; m >>= 1)
#pragma unroll
        for (int b = 0; b < NB; ++b) r[b] += __shfl_xor(r[b], m);
    if (lane < NB) cond[lane * DD + row] = r[lane] + lb[row];
}

__global__ __launch_bounds__(256) void k_film(const float* __restrict__ cond,
                                              const float* __restrict__ fw,
                                              const float* __restrict__ fb,
                                              float* __restrict__ gbv) {
    __shared__ float sc[NB * DD];
    for (int i = threadIdx.x * 4; i < NB * DD; i += 1024)
        *(float4*)&sc[i] = *(const float4*)&cond[i];
    __syncthreads();
    const int w = threadIdx.x >> 6, lane = threadIdx.x & 63;
    const int row = blockIdx.x * 4 + w;
    float wv[8];
#pragma unroll
    for (int j = 0; j < 8; ++j) wv[j] = fw[(size_t)row * DD + lane + 64 * j];
    float r[NB];
#pragma unroll
    for (int b = 0; b < NB; ++b) {
        float s = 0.f;
#pragma unroll
        for (int j = 0; j < 8; ++j) s += wv[j] * sc[b * DD + lane + 64 * j];
        r[b] = s;
    }
#pragma unroll
    for (int m = 32; m >= 1; m >>= 1)
#pragma unroll
        for (int b = 0; b < NB; ++b) r[b] += __shfl_xor(r[b], m);
    if (lane < NB) gbv[lane * 2 * DD + row] = r[lane] + fb[row];
}

// ---------------------------------------------------------------------------
// VQ dist MFMA + fused per-block argmin. Grid 512 (1D, XCD-chunked).
// ---------------------------------------------------------------------------
__global__ __launch_bounds__(256, 2) void k_dist(const u16* __restrict__ Ahg,
                                                 const u16* __restrict__ Alg,
                                                 const u16* __restrict__ Bhg,
                                                 const u16* __restrict__ Blg,
                                                 const float* __restrict__ cbn,
                                                 float* __restrict__ pmin,
                                                 int* __restrict__ pidx) {
    __shared__ __align__(16) u16 Ah[2][4096], Al[2][4096], Bh[2][4096], Bl[2][4096];
    __shared__ float s_best[128][2];
    __shared__ int s_bidx[128][2];
    const int tid = threadIdx.x;
    const int l = tid & 63, w = tid >> 6, wm = w >> 1, wn = w & 1;
    const int lane16 = l & 15, laneK = l >> 4;
    const int g = blockIdx.x;
    const int xcd = g & 7, slot = g >> 3;
    const int f0 = (xcd * 8 + (slot & 7)) * 128;
    const int cy = slot >> 3;
    const int c0 = cy * 128;

    const int p0 = w * 128 + l, p1 = p0 + 64;
    const int r0 = p0 >> 2, q0 = (p0 & 3) ^ ((r0 >> 1) & 3);
    const int r1 = p1 >> 2, q1 = (p1 & 3) ^ ((r1 >> 1) & 3);
    const u16* gA0h = Ahg + (size_t)(f0 + r0) * DD + q0 * 8;
    const u16* gA1h = Ahg + (size_t)(f0 + r1) * DD + q1 * 8;
    const u16* gA0l = Alg + (size_t)(f0 + r0) * DD + q0 * 8;
    const u16* gA1l = Alg + (size_t)(f0 + r1) * DD + q1 * 8;
    const u16* gB0h = Bhg + (size_t)(c0 + r0) * DD + q0 * 8;
    const u16* gB1h = Bhg + (size_t)(c0 + r1) * DD + q1 * 8;
    const u16* gB0l = Blg + (size_t)(c0 + r0) * DD + q0 * 8;
    const u16* gB1l = Blg + (size_t)(c0 + r1) * DD + q1 * 8;

    int offA[4], offB[4];
#pragma unroll
    for (int i = 0; i < 4; ++i) {
        int ra = wm * 64 + i * 16 + lane16;
        offA[i] = (ra * 4 + (laneK ^ ((ra >> 1) & 3))) * 8;
        int rb = wn * 64 + i * 16 + lane16;
        offB[i] = (rb * 4 + (laneK ^ ((rb >> 1) & 3))) * 8;
    }

    f4 zero = {0.f, 0.f, 0.f, 0.f};
    f4 acc[4][4];
#pragma unroll
    for (int i = 0; i < 4; ++i)
#pragma unroll
        for (int j = 0; j < 4; ++j) acc[i][j] = zero;

    auto stg = [&](int buf, int kt) {
        gld16(gA0h + kt, Ah[buf] + w * 1024);
        gld16(gA1h + kt, Ah[buf] + w * 1024 + 512);
        gld16(gA0l + kt, Al[buf] + w * 1024);
        gld16(gA1l + kt, Al[buf] + w * 1024 + 512);
        gld16(gB0h + kt, Bh[buf] + w * 1024);
        gld16(gB1h + kt, Bh[buf] + w * 1024 + 512);
        gld16(gB0l + kt, Bl[buf] + w * 1024);
        gld16(gB1l + kt, Bl[buf] + w * 1024 + 512);
    };
    auto compute = [&](int buf) {
        b8 ah[4], al[4], bh[4], bl[4];
#pragma unroll
        for (int i = 0; i < 4; ++i) {
            ah[i] = *(const b8*)(Ah[buf] + offA[i]);
            al[i] = *(const b8*)(Al[buf] + offA[i]);
            bh[i] = *(const b8*)(Bh[buf] + offB[i]);
            bl[i] = *(const b8*)(Bl[buf] + offB[i]);
        }
#pragma unroll
        for (int mi = 0; mi < 4; ++mi)
#pragma unroll
            for (int ni = 0; ni < 4; ++ni) {
                acc[mi][ni] = mfma(ah[mi], bh[ni], acc[mi][ni]);
                acc[mi][ni] = mfma(ah[mi], bl[ni], acc[mi][ni]);
                acc[mi][ni] = mfma(al[mi], bh[ni], acc[mi][ni]);
            }
    };

    PIPELINE(16, 32)

    float cbv[4];
    int cidx[4];
#pragma unroll
    for (int ni = 0; ni < 4; ++ni) {
        cidx[ni] = c0 + wn * 64 + ni * 16 + lane16;
        cbv[ni] = cbn[cidx[ni]];
    }
#pragma unroll
    for (int mi = 0; mi < 4; ++mi)
#pragma unroll
        for (int q = 0; q < 4; ++q) {
            float best = 3.4e38f;
            int bi = 0x7fffffff;
#pragma unroll
            for (int ni = 0; ni < 4; ++ni) {
                float s = cbv[ni] - 2.0f * acc[mi][ni][q];
                if (s < best || (s == best && cidx[ni] < bi)) { best = s; bi = cidx[ni]; }
            }
#pragma unroll
            for (int m = 8; m >= 1; m >>= 1) {
                float os = __shfl_xor(best, m);
                int oi = __shfl_xor(bi, m);
                if (os < best || (os == best && oi < bi)) { best = os; bi = oi; }
            }
            if (lane16 == 0) {
                int rl = wm * 64 + mi * 16 + laneK * 4 + q;
                s_best[rl][wn] = best;
                s_bidx[rl][wn] = bi;
            }
        }
    __syncthreads();
    if (tid < 128) {
        float b0 = s_best[tid][0], b1 = s_best[tid][1];
        int i0 = s_bidx[tid][0], i1 = s_bidx[tid][1];
        bool t1 = (b1 < b0) || (b1 == b0 && i1 < i0);
        int f = f0 + tid;
        if (f < FR) {
            pmin[f * 8 + cy] = t1 ? b1 : b0;
            pidx[f * 8 + cy] = t1 ? i1 : i0;
        }
    }
}

// ---------------------------------------------------------------------------
// Decoder MFMA GEMM with FUSED combine + gather + FiLM + split in A-staging.
// Counted-vmcnt B prefetch: A float4 loads issued BEFORE the gld16s so their
// consumption (split8) does not drain the B prefetch (vmcnt drains in issue
// order). Wait is vmcnt(4) lgkmcnt(0): current B tile done, next tile flying.
// ---------------------------------------------------------------------------
struct AV {
    float4 c00, c01, g00, g01, e00, e01;
    float4 c10, c11, g10, g11, e10, e11;
};

__global__ __launch_bounds__(256, 2) void k_dec(const float* __restrict__ pmin,
                                                const int* __restrict__ pidx,
                                                const float* __restrict__ cb,
                                                const float* __restrict__ gbv,
                                                const u16* __restrict__ Bhg,
                                                const u16* __restrict__ Blg,
                                                const float* __restrict__ db,
                                                float* __restrict__ out) {
    __shared__ __align__(16) u16 Ah[2][4096], Al[2][4096], Bh[2][4096], Bl[2][4096];
    __shared__ int codes_lds[128];
    __shared__ int b_lds[128];
    const int tid = threadIdx.x;
    const int l = tid & 63, w = tid >> 6, wm = w >> 1, wn = w & 1;
    const int lane16 = l & 15, laneK = l >> 4;
    const int f0 = blockIdx.y * 128, s0 = blockIdx.x * 128;

    // combine partial argmins -> codes for this f-panel
    if (tid < 128) {
        int f = f0 + tid;
        int fc = (f < FR) ? f : FR - 1;
        float best = pmin[fc * 8];
        int bi = pidx[fc * 8];
#pragma unroll
        for (int y = 1; y < 8; ++y) {
            float s = pmin[fc * 8 + y];
            if (s < best) { best = s; bi = pidx[fc * 8 + y]; }
        }
        codes_lds[tid] = bi;
        b_lds[tid] = fc / TT;
    }
    __syncthreads();

    // B staging (gld16)
    const int p0 = w * 128 + l, p1 = p0 + 64;
    const int r0 = p0 >> 2, q0 = (p0 & 3) ^ ((r0 >> 1) & 3);
    const int r1 = p1 >> 2, q1 = (p1 & 3) ^ ((r1 >> 1) & 3);
    const u16* gB0h = Bhg + (size_t)(s0 + r0) * DD + q0 * 8;
    const u16* gB1h = Bhg + (size_t)(s0 + r1) * DD + q1 * 8;
    const u16* gB0l = Blg + (size_t)(s0 + r0) * DD + q0 * 8;
    const u16* gB1l = Blg + (size_t)(s0 + r1) * DD + q1 * 8;

    // A staging (reg->ds_write): rows ra0 (0..63), ra1 (64..127)
    const int pa0 = tid, pa1 = tid + 256;
    const int ra0 = pa0 >> 2, qa0 = (pa0 & 3) ^ ((ra0 >> 1) & 3);
    const int ra1 = pa1 >> 2, qa1 = (pa1 & 3) ^ ((ra1 >> 1) & 3);
    const float* cp0 = cb + (size_t)codes_lds[ra0] * DD + qa0 * 8;
    const float* cp1 = cb + (size_t)codes_lds[ra1] * DD + qa1 * 8;
    const float* gp0 = gbv + b_lds[ra0] * 2 * DD + qa0 * 8;
    const float* gp1 = gbv + b_lds[ra1] * 2 * DD + qa1 * 8;

    int offA[4], offB[4];
#pragma unroll
    for (int i = 0; i < 4; ++i) {
        int ra = wm * 64 + i * 16 + lane16;
        offA[i] = (ra * 4 + (laneK ^ ((ra >> 1) & 3))) * 8;
        int rb = wn * 64 + i * 16 + lane16;
        offB[i] = (rb * 4 + (laneK ^ ((rb >> 1) & 3))) * 8;
    }

    f4 zero = {0.f, 0.f, 0.f, 0.f};
    f4 acc[4][4];
#pragma unroll
    for (int i = 0; i < 4; ++i)
#pragma unroll
        for (int j = 0; j < 4; ++j) acc[i][j] = zero;

    auto stgB = [&](int buf, int kt) {
        gld16(gB0h + kt, Bh[buf] + w * 1024);
        gld16(gB1h + kt, Bh[buf] + w * 1024 + 512);
        gld16(gB0l + kt, Bl[buf] + w * 1024);
        gld16(gB1l + kt, Bl[buf] + w * 1024 + 512);
    };
    auto loadA = [&](int kt) {
        AV v;
        v.c00 = *(const float4*)(cp0 + kt);
        v.c01 = *(const float4*)(cp0 + kt + 4);
        v.g00 = *(const float4*)(gp0 + kt);
        v.g01 = *(const float4*)(gp0 + kt + 4);
        v.e00 = *(const float4*)(gp0 + DD + kt);
        v.e01 = *(const float4*)(gp0 + DD + kt + 4);
        v.c10 = *(const float4*)(cp1 + kt);
        v.c11 = *(const float4*)(cp1 + kt + 4);
        v.g10 = *(const float4*)(gp1 + kt);
        v.g11 = *(const float4*)(gp1 + kt + 4);
        v.e10 = *(const float4*)(gp1 + DD + kt);
        v.e11 = *(const float4*)(gp1 + DD + kt + 4);
        return v;
    };
    auto writeA = [&](int buf, const AV& v) {
        float4 m00, m01, m10, m11;
        m00.x = v.g00.x * v.c00.x + v.e00.x; m00.y = v.g00.y * v.c00.y + v.e00.y;
        m00.z = v.g00.z * v.c00.z + v.e00.z; m00.w = v.g00.w * v.c00.w + v.e00.w;
        m01.x = v.g01.x * v.c01.x + v.e01.x; m01.y = v.g01.y * v.c01.y + v.e01.y;
        m01.z = v.g01.z * v.c01.z + v.e01.z; m01.w = v.g01.w * v.c01.w + v.e01.w;
        m10.x = v.g10.x * v.c10.x + v.e10.x; m10.y = v.g10.y * v.c10.y + v.e10.y;
        m10.z = v.g10.z * v.c10.z + v.e10.z; m10.w = v.g10.w * v.c10.w + v.e10.w;
        m11.x = v.g11.x * v.c11.x + v.e11.x; m11.y = v.g11.y * v.c11.y + v.e11.y;
        m11.z = v.g11.z * v.c11.z + v.e11.z; m11.w = v.g11.w * v.c11.w + v.e11.w;
        split8(m00, m01, Ah[buf] + pa0 * 8, Al[buf] + pa0 * 8);
        split8(m10, m11, Ah[buf] + pa1 * 8, Al[buf] + pa1 * 8);
    };
    auto compute = [&](int buf) {
        b8 ah[4], al[4], bh[4], bl[4];
#pragma unroll
        for (int i = 0; i < 4; ++i) {
            ah[i] = *(const b8*)(Ah[buf] + offA[i]);
            al[i] = *(const b8*)(Al[buf] + offA[i]);
            bh[i] = *(const b8*)(Bh[buf] + offB[i]);
            bl[i] = *(const b8*)(Bl[buf] + offB[i]);
        }
#pragma unroll
        for (int mi = 0; mi < 4; ++mi)
#pragma unroll
            for (int ni = 0; ni < 4; ++ni) {
                acc[mi][ni] = mfma(ah[mi], bh[ni], acc[mi][ni]);
                acc[mi][ni] = mfma(ah[mi], bl[ni], acc[mi][ni]);
                acc[mi][ni] = mfma(al[mi], bh[ni], acc[mi][ni]);
            }
    };

    // prologue: A floats first (older), then gld16s, then writes
    {
        AV v0 = loadA(0);
        AV v1 = loadA(32);
        stgB(0, 0);
        stgB(1, 32);
        writeA(0, v0);
        writeA(1, v1);
    }
    int cur = 0;
    for (int t = 0; t < 16; ++t) {
        if (t < 15) asm volatile("s_waitcnt vmcnt(4) lgkmcnt(0)" ::: "memory");
        else        asm volatile("s_waitcnt vmcnt(0) lgkmcnt(0)" ::: "memory");
        __builtin_amdgcn_s_barrier();
        asm volatile("" ::: "memory");
        compute(cur);
        asm volatile("" ::: "memory");
        __builtin_amdgcn_s_barrier();
        if (t < 14) {
            AV v = loadA((t + 2) * 32);   // floats issued before gld16s
            stgB(cur, (t + 2) * 32);
            writeA(cur, v);
        }
        cur ^= 1;
    }

    const float d0v = db[0];
#pragma unroll
    for (int mi = 0; mi < 4; ++mi)
#pragma unroll
        for (int q = 0; q < 4; ++q) {
            int f = f0 + wm * 64 + mi * 16 + laneK * 4 + q;
            if (f < FR) {
#pragma unroll
                for (int ni = 0; ni < 4; ++ni) {
                    int s = s0 + wn * 64 + ni * 16 + lane16;
                    if (s < KSZ) out[(size_t)f * KSZ + s] = acc[mi][ni][q] + d0v;
                }
            }
        }
}

// ---------------------------------------------------------------------------
extern "C" void kernel_launch(void* const* d_in, const int* in_sizes, int n_in,
                              void* d_out, int out_size, void* d_ws, size_t ws_size,
                              hipStream_t stream) {
    const float* wav    = (const float*)d_in[0];
    const float* enc_w  = (const float*)d_in[1];
    const float* enc_b  = (const float*)d_in[2];
    const float* cb     = (const float*)d_in[3];
    const float* lin_w  = (const float*)d_in[4];
    const float* lin_b  = (const float*)d_in[5];
    const float* film_w = (const float*)d_in[6];
    const float* film_b = (const float*)d_in[7];
    const float* dec_w  = (const float*)d_in[8];
    const float* dec_b  = (const float*)d_in[9];
    float* out = (float*)d_out;

    char* p = (char*)d_ws;
    u16* embh = (u16*)p;                 p += (size_t)FRP * DD * 2;
    u16* embl = (u16*)p;                 p += (size_t)FRP * DD * 2;
    u16* wavh = (u16*)p;                 p += (size_t)FR * KSZ * 2;
    u16* wavl = (u16*)p;                 p += (size_t)FR * KSZ * 2;
    u16* ewh  = (u16*)p;                 p += (size_t)DD * KSZ * 2;
    u16* ewl  = (u16*)p;                 p += (size_t)DD * KSZ * 2;
    u16* cbh  = (u16*)p;                 p += (size_t)CK * DD * 2;
    u16* cbl  = (u16*)p;                 p += (size_t)CK * DD * 2;
    u16* dwfh = (u16*)p;                 p += (size_t)384 * DD * 2;
    u16* dwfl = (u16*)p;                 p += (size_t)384 * DD * 2;
    float* cbn  = (float*)p;             p += CK * 4;
    float* tsum = (float*)p;             p += NB * DD * 4;
    float* cond = (float*)p;             p += NB * DD * 4;
    float* gbv  = (float*)p;             p += NB * 2 * DD * 4;
    float* pmin = (float*)p;             p += FR * 8 * 4;
    int*   pidx = (int*)p;               p += FR * 8 * 4;

    k_prep<<<dim3(1667), 256, 0, stream>>>(enc_w, ewh, ewl, cb, cbh, cbl,
                                           dec_w, dwfh, dwfl, cbn, wav, wavh, wavl, tsum);
    k_enc<<<dim3(256), 256, 0, stream>>>(wavh, wavl, ewh, ewl, enc_b, embh, embl, tsum);
    k_cond<<<dim3(128), 256, 0, stream>>>(tsum, lin_w, lin_b, cond);
    k_film<<<dim3(256), 256, 0, stream>>>(cond, film_w, film_b, gbv);
    k_dist<<<dim3(512), 256, 0, stream>>>(embh, embl, cbh, cbl, cbn, pmin, pidx);
    k_dec<<<dim3(3, 63), 256, 0, stream>>>(pmin, pidx, cb, gbv, dwfh, dwfl, dec_b, out);
}